// Round 6
// baseline (1890.705 us; speedup 1.0000x reference)
//
#include <hip/hip_runtime.h>
#include <hip/hip_bf16.h>
#include <math.h>

// Problem constants
#define BB 2
#define TT 4
#define CIN 128
#define DM 256
#define NQ 300
#define NP 8
#define PS 3
#define NL 6
#define HW 4096   // 64*64
#define KP 2304   // 3*3*256

typedef __attribute__((ext_vector_type(8))) short short8;
typedef __attribute__((ext_vector_type(4))) float f32x4;
typedef unsigned short ushort_t;

static __device__ __forceinline__ ushort_t f2bf(float f) {
  __hip_bfloat16 h = __float2bfloat16(f);
  return *reinterpret_cast<ushort_t*>(&h);
}
static __device__ __forceinline__ float bf2f(ushort_t u) {
  return __uint_as_float(((unsigned)u) << 16);
}

// ---------------------------------------------------------------------------
// ONE mega weight-prep kernel (block-range ladder):
//  [0,4385)        : plain fp32->bf16 converts (w_in|w_lat|Wp2|Wo|w_b1|Wp1)
//  [4385,4641)     : tct (temporal-conv coeffs, transposed)
//  [4641,6945)     : wsm reorder+convert
//  [6945,10017)    : wqr merge (w_r1 | Wq)
//  [10017,10029)   : bqr merge (b_r1 | bq)
__global__ void k_prep(const float* __restrict__ w_in, const float* __restrict__ w_lat,
                       const float* __restrict__ Wp2, const float* __restrict__ Wo,
                       const float* __restrict__ w_b1, const float* __restrict__ Wp1,
                       ushort_t* __restrict__ win_bf, ushort_t* __restrict__ wlat_bf,
                       ushort_t* __restrict__ wp2_bf, ushort_t* __restrict__ wo_bf,
                       ushort_t* __restrict__ wb1_bf, ushort_t* __restrict__ wp1_bf,
                       const float* __restrict__ w_tf, ushort_t* __restrict__ tct,
                       const float* __restrict__ w_sm, ushort_t* __restrict__ wsm_bf,
                       const float* __restrict__ w_r1, const float* __restrict__ Wq,
                       ushort_t* __restrict__ wqr_bf,
                       const float* __restrict__ b_r1, const float* __restrict__ bq,
                       float* __restrict__ bqr) {
  int b = blockIdx.x, t = threadIdx.x;
  if (b < 4385) {
    int i = b * 256 + t;
    const float* s; ushort_t* d; int base;
    if (i < 8192)         { s = w_in;  d = win_bf;  base = 0; }
    else if (i < 24576)   { s = w_lat; d = wlat_bf; base = 8192; }
    else if (i < 122880)  { s = Wp2;   d = wp2_bf;  base = 24576; }
    else if (i < 221184)  { s = Wo;    d = wo_bf;   base = 122880; }
    else if (i < 237568)  { s = w_b1;  d = wb1_bf;  base = 221184; }
    else if (i < 1122304) { s = Wp1;   d = wp1_bf;  base = 237568; }
    else return;
    int j = i - base;
    float4 v = ((const float4*)s)[j];
    d[j * 4 + 0] = f2bf(v.x);
    d[j * 4 + 1] = f2bf(v.y);
    d[j * 4 + 2] = f2bf(v.z);
    d[j * 4 + 3] = f2bf(v.w);
  } else if (b < 4641) {
    int i = (b - 4385) * 256 + t;     // < 512*128
    int k = i >> 7, c = i & 127;
    int u = k >> 7, ci = k & 127;
    const float* wp = w_tf + ((size_t)(c * 128 + ci)) * 3;
    float w0 = wp[0], w1 = wp[1], w2 = wp[2];
    float coef = (u == 0) ? (w0 + w1) : (u == 3) ? (w1 + w2) : (w0 + w1 + w2);
    tct[(size_t)k * 128 + c] = f2bf(0.25f * coef);
  } else if (b < 6945) {
    int i = (b - 4641) * 256 + t;     // < 256*2304
    int n = i / KP;
    int r = i - n * KP;
    int tp = r >> 8, c = r & 255;
    wsm_bf[i] = f2bf(w_sm[((size_t)(n * 256 + c)) * 9 + tp]);
  } else if (b < 10017) {
    int i = (b - 6945) * 256 + t;     // < 6*512*256
    int l = i / (512 * 256);
    int r = i - l * 512 * 256;
    int n = r >> 8, c = r & 255;
    float v = (n < 256) ? w_r1[n * 256 + c] : Wq[((size_t)l * 256 + (n - 256)) * 256 + c];
    wqr_bf[i] = f2bf(v);
  } else {
    int i = (b - 10017) * 256 + t;    // < 6*512
    if (i >= NL * 512) return;
    int l = i >> 9, n = i & 511;
    bqr[i] = (n < 256) ? b_r1[n] : bq[l * 256 + n - 256];
  }
}

// bias_comb[d] = b_in[d] + sum_c w_in[d,c]*b_tf[c]   (1 block, 256 threads)
__global__ void k_bcomb(const float* __restrict__ w_in, const float* __restrict__ b_tf,
                        const float* __restrict__ b_in, float* __restrict__ bias_comb) {
  __shared__ float bt[128];
  int d = threadIdx.x;
  if (d < 128) bt[d] = b_tf[d];
  __syncthreads();
  float a = b_in[d];
  for (int c = 0; c < 128; ++c) a += w_in[d * 128 + c] * bt[c];
  bias_comb[d] = a;
}

// ---------------------------------------------------------------------------
// Fused backbone GEMM: xcl[b*HW+s][d] = bf16( feat_t[s][:] . Wcomb[d][:] +
//                                             bias_comb[d] + pos(d, y, x) )
__global__ __launch_bounds__(256) void k_feat(const float* __restrict__ feat,
                                              const ushort_t* __restrict__ wcomb,
                                              const float* __restrict__ bias_comb,
                                              ushort_t* __restrict__ xcl) {
  __shared__ ushort_t As[64 * 36];
  __shared__ ushort_t Bs[64 * 36];
  __shared__ float dimt_s[256];
  int tid = threadIdx.x;
  {
    int dd = tid & 127;
    int ii = dd >> 1;
    float e = (2.0f * (float)(ii >> 1)) / 64.0f;
    dimt_s[tid] = powf(10000.0f, e);
  }
  int bm = blockIdx.x * 64, bn = blockIdx.y * 64;
  int b = bm >> 12;
  int s0 = bm & 4095;
  int w = tid >> 6, lane = tid & 63;
  int wm = (w & 1) * 32, wn = (w >> 1) * 32;
  int q = lane >> 4, ml = lane & 15;
  int srow = tid >> 2, scol = (tid & 3) * 8;
  const ushort_t* Wg = wcomb + (size_t)(bn + srow) * 512 + scol;
  f32x4 acc[2][2] = {};
  for (int k0 = 0; k0 < 512; k0 += 32) {
    short8 wv = *(const short8*)(Wg + k0);
#pragma unroll
    for (int j = 0; j < 8; ++j) {
      int kk = w * 8 + j;
      int k = k0 + kk;
      int u = k >> 7, ci = k & 127;
      float v = feat[(((size_t)(b * 4 + u) * 128 + ci) << 12) + s0 + lane];
      As[lane * 36 + kk] = f2bf(v);
    }
    *(short8*)(Bs + srow * 36 + scol) = wv;
    __syncthreads();
    short8 a0 = *(const short8*)(As + (wm + ml) * 36 + q * 8);
    short8 a1 = *(const short8*)(As + (wm + 16 + ml) * 36 + q * 8);
    short8 b0 = *(const short8*)(Bs + (wn + ml) * 36 + q * 8);
    short8 b1 = *(const short8*)(Bs + (wn + 16 + ml) * 36 + q * 8);
    acc[0][0] = __builtin_amdgcn_mfma_f32_16x16x32_bf16(a0, b0, acc[0][0], 0, 0, 0);
    acc[0][1] = __builtin_amdgcn_mfma_f32_16x16x32_bf16(a0, b1, acc[0][1], 0, 0, 0);
    acc[1][0] = __builtin_amdgcn_mfma_f32_16x16x32_bf16(a1, b0, acc[1][0], 0, 0, 0);
    acc[1][1] = __builtin_amdgcn_mfma_f32_16x16x32_bf16(a1, b1, acc[1][1], 0, 0, 0);
    __syncthreads();
  }
  const float FKT = 6.28318530717958647692f / 64.000001f;
#pragma unroll
  for (int i2 = 0; i2 < 2; ++i2) {
#pragma unroll
    for (int j2 = 0; j2 < 2; ++j2) {
      int cn = bn + wn + j2 * 16 + ml;
      float dimt = dimt_s[cn];
      float bC = bias_comb[cn];
      bool isx = cn >= 128;
      bool isc = cn & 1;
#pragma unroll
      for (int r = 0; r < 4; ++r) {
        int rm = bm + wm + i2 * 16 + q * 4 + r;
        int s = rm & 4095;
        int y = s >> 6, x = s & 63;
        float ang = (float)((isx ? x : y) + 1) * FKT / dimt;
        float pos = isc ? cosf(ang) : sinf(ang);
        xcl[(size_t)rm * 256 + cn] = f2bf(acc[i2][j2][r] + bC + pos);
      }
    }
  }
}

// ---------------------------------------------------------------------------
__global__ void k_zero(uint4* __restrict__ p, int n) {
  int i = blockIdx.x * 256 + threadIdx.x;
  if (i < n) p[i] = make_uint4(0u, 0u, 0u, 0u);
}

// ---------------------------------------------------------------------------
// bf16 MFMA GEMM, BM=BN=64, BK=32.  A (M,K), W (N,K) bf16 row-major.
// OUTMODE: 0 = fp32 C (bias+ACT)
//          1 = bf16 into padded (B,66,66,256)
//          2 = fp32 C + bf16 mirror Cb, with residual add (res)
//          4 = split: n<256 -> relu -> Cf ; n>=256 -> (float*)Cb  (N=512)
//          6 = plain bf16 out Cb (row-major M x N)
template <int ACT, int OUTMODE, int MG>
__global__ __launch_bounds__(256) void k_gemm_bf16(const ushort_t* __restrict__ A,
                                                   const ushort_t* __restrict__ W,
                                                   const float* __restrict__ bias,
                                                   const float* __restrict__ res,
                                                   float* __restrict__ Cf,
                                                   ushort_t* __restrict__ Cb,
                                                   int M, int N, int K) {
  __shared__ ushort_t As[64 * 36];
  __shared__ ushort_t Bs[64 * 36];
  int tid = threadIdx.x;
  int bm = blockIdx.x * 64, bn = blockIdx.y * 64;
  int w = tid >> 6, lane = tid & 63;
  int wm = (w & 1) * 32, wn = (w >> 1) * 32;
  int q = lane >> 4, ml = lane & 15;
  f32x4 acc[2][2] = {};
  int srow = tid >> 2, scol = (tid & 3) * 8;
  int ga = bm + srow;
  if (MG) ga = min(ga, M - 1);
  const ushort_t* Ag = A + (size_t)ga * K + scol;
  const ushort_t* Wg = W + (size_t)(bn + srow) * K + scol;
  for (int k0 = 0; k0 < K; k0 += 32) {
    short8 av = *(const short8*)(Ag + k0);
    short8 wv = *(const short8*)(Wg + k0);
    *(short8*)(As + srow * 36 + scol) = av;
    *(short8*)(Bs + srow * 36 + scol) = wv;
    __syncthreads();
    short8 a0 = *(const short8*)(As + (wm + ml) * 36 + q * 8);
    short8 a1 = *(const short8*)(As + (wm + 16 + ml) * 36 + q * 8);
    short8 b0 = *(const short8*)(Bs + (wn + ml) * 36 + q * 8);
    short8 b1 = *(const short8*)(Bs + (wn + 16 + ml) * 36 + q * 8);
    acc[0][0] = __builtin_amdgcn_mfma_f32_16x16x32_bf16(a0, b0, acc[0][0], 0, 0, 0);
    acc[0][1] = __builtin_amdgcn_mfma_f32_16x16x32_bf16(a0, b1, acc[0][1], 0, 0, 0);
    acc[1][0] = __builtin_amdgcn_mfma_f32_16x16x32_bf16(a1, b0, acc[1][0], 0, 0, 0);
    acc[1][1] = __builtin_amdgcn_mfma_f32_16x16x32_bf16(a1, b1, acc[1][1], 0, 0, 0);
    __syncthreads();
  }
#pragma unroll
  for (int i = 0; i < 2; ++i) {
#pragma unroll
    for (int j = 0; j < 2; ++j) {
      int cn = bn + wn + j * 16 + ml;
      float bsv = bias ? bias[cn] : 0.f;
#pragma unroll
      for (int r = 0; r < 4; ++r) {
        int rm = bm + wm + i * 16 + q * 4 + r;
        if (MG && rm >= M) continue;
        float v = acc[i][j][r] + bsv;
        if (OUTMODE == 0) {
          if (ACT == 1) v = fmaxf(v, 0.f);
          Cf[(size_t)rm * N + cn] = v;
        } else if (OUTMODE == 1) {
          int b = rm >> 12, rem = rm & 4095;
          int y = rem >> 6, xx = rem & 63;
          Cb[(((size_t)(b * 66 + y + 1)) * 66 + xx + 1) * 256 + cn] = f2bf(v);
        } else if (OUTMODE == 2) {
          v += res[(size_t)rm * N + cn];
          Cf[(size_t)rm * N + cn] = v;
          Cb[(size_t)rm * N + cn] = f2bf(v);
        } else if (OUTMODE == 4) {
          if (cn < 256) Cf[(size_t)rm * 256 + cn] = fmaxf(v, 0.f);
          else ((float*)Cb)[(size_t)rm * 256 + cn - 256] = v;
        } else if (OUTMODE == 6) {
          Cb[(size_t)rm * N + cn] = f2bf(v);
        }
      }
    }
  }
}

// ---------------------------------------------------------------------------
// Full-N GEMM: BM=64, BN=256, BK=32, 256 threads (4 waves, each 64x64).
// GATHER: 1 = A from padded x2p (B,66,66,256); k = tap*256 + c   [conv3]
//         2 = A bilinear-sampled from fcl via ref               [Wp1 fused]
// OUT:    0 = relu + mean over groups of 8 m-rows -> Cb (600x256) [pvm]
//         1 = bias + bf16 -> Cb (M x 256)                         [fcl]
template <int GATHER, int OUT>
__global__ __launch_bounds__(256) void k_gemm_n256(const ushort_t* __restrict__ A,
                                                   const ushort_t* __restrict__ W,
                                                   const float* __restrict__ bias,
                                                   const float* __restrict__ ref,
                                                   ushort_t* __restrict__ Cb,
                                                   int M, int K) {
  __shared__ ushort_t sm[17408];     // As 64*36 | Bs 256*36 (11520); red 64*272
  ushort_t* As = sm;
  ushort_t* Bs = sm + 64 * 36;
  int tid = threadIdx.x;
  int bm = blockIdx.x * 64;
  int w = tid >> 6, lane = tid & 63;
  int q = lane >> 4, ml = lane & 15;
  f32x4 acc[4][4] = {};
  int ar = tid >> 2, ac = (tid & 3) * 8;
  size_t pbase = 0;
  float rx = 0.f, ry = 0.f;
  const ushort_t* fb = nullptr;
  if (GATHER == 1) {
    int s = bm + ar;
    int b = s >> 12, rem = s & 4095;
    pbase = ((size_t)(b * 66 + (rem >> 6)) * 66 + (rem & 63)) * 256;
  } else {
    int row = bm + ar;
    int qrow = row >> 3, p = row & 7;
    rx = ref[qrow * 16 + p * 2 + 0];
    ry = ref[qrow * 16 + p * 2 + 1];
    fb = A + (size_t)(qrow / NQ) * HW * 256;
  }
  const ushort_t* Wg = W + (size_t)tid * K;
  for (int k0 = 0; k0 < K; k0 += 32) {
    int ka = k0 + ac;
    short8 av;
    if (GATHER == 1) {
      int t9 = ka >> 8;
      int ky = t9 / 3, kx = t9 - ky * 3;
      av = *(const short8*)(A + pbase + (size_t)(ky * 66 + kx) * 256 + (ka & 255));
    } else {
      int t9 = ka >> 8;
      int jy = t9 / 3, jx = t9 - jy * 3;
      int c = ka & 255;
      float yy = fminf(fmaxf((ry + (float)(jy - 1) * (1.0f / 64.0f)) * 63.0f, 0.f), 63.0f);
      float y0f = floorf(yy);
      float wy = yy - y0f;
      int y0 = (int)y0f, y1 = min(y0 + 1, 63);
      float xx = fminf(fmaxf((rx + (float)(jx - 1) * (1.0f / 64.0f)) * 63.0f, 0.f), 63.0f);
      float x0f = floorf(xx);
      float wx = xx - x0f;
      int x0 = (int)x0f, x1 = min(x0 + 1, 63);
      const ushort_t* r0 = fb + (size_t)(y0 * 64) * 256 + c;
      const ushort_t* r1 = fb + (size_t)(y1 * 64) * 256 + c;
      short8 p00 = *(const short8*)(r0 + x0 * 256);
      short8 p01 = *(const short8*)(r0 + x1 * 256);
      short8 p10 = *(const short8*)(r1 + x0 * 256);
      short8 p11 = *(const short8*)(r1 + x1 * 256);
      float w00 = (1.f - wx) * (1.f - wy), w01 = wx * (1.f - wy);
      float w10 = (1.f - wx) * wy, w11 = wx * wy;
#pragma unroll
      for (int j = 0; j < 8; ++j) {
        float v = w00 * bf2f((ushort_t)p00[j]) + w01 * bf2f((ushort_t)p01[j]) +
                  w10 * bf2f((ushort_t)p10[j]) + w11 * bf2f((ushort_t)p11[j]);
        av[j] = (short)f2bf(v);
      }
    }
    short8 wv0 = *(const short8*)(Wg + k0 + 0);
    short8 wv1 = *(const short8*)(Wg + k0 + 8);
    short8 wv2 = *(const short8*)(Wg + k0 + 16);
    short8 wv3 = *(const short8*)(Wg + k0 + 24);
    *(short8*)(As + ar * 36 + ac) = av;
    *(short8*)(Bs + tid * 36 + 0) = wv0;
    *(short8*)(Bs + tid * 36 + 8) = wv1;
    *(short8*)(Bs + tid * 36 + 16) = wv2;
    *(short8*)(Bs + tid * 36 + 24) = wv3;
    __syncthreads();
    short8 bfr[4];
#pragma unroll
    for (int j = 0; j < 4; ++j)
      bfr[j] = *(const short8*)(Bs + (w * 64 + j * 16 + ml) * 36 + q * 8);
#pragma unroll
    for (int i = 0; i < 4; ++i) {
      short8 a = *(const short8*)(As + (i * 16 + ml) * 36 + q * 8);
#pragma unroll
      for (int j = 0; j < 4; ++j)
        acc[i][j] = __builtin_amdgcn_mfma_f32_16x16x32_bf16(a, bfr[j], acc[i][j], 0, 0, 0);
    }
    __syncthreads();
  }
  if (OUT == 1) {
#pragma unroll
    for (int i = 0; i < 4; ++i)
#pragma unroll
      for (int j = 0; j < 4; ++j) {
        int cn = w * 64 + j * 16 + ml;
        float bsv = bias[cn];
#pragma unroll
        for (int r = 0; r < 4; ++r) {
          int rm = bm + i * 16 + q * 4 + r;
          Cb[(size_t)rm * 256 + cn] = f2bf(acc[i][j][r] + bsv);
        }
      }
    return;
  }
  // OUT==0: relu + pmean(8) -> Cb rows bm/8 .. bm/8+7
  __syncthreads();
  ushort_t* red = sm;   // 64 x 272
#pragma unroll
  for (int i = 0; i < 4; ++i)
#pragma unroll
    for (int j = 0; j < 4; ++j) {
      int cl = w * 64 + j * 16 + ml;
      float bsv = bias[cl];
#pragma unroll
      for (int r = 0; r < 4; ++r) {
        int rl = i * 16 + q * 4 + r;
        red[rl * 272 + cl] = f2bf(fmaxf(acc[i][j][r] + bsv, 0.f));
      }
    }
  __syncthreads();
#pragma unroll
  for (int g = 0; g < 8; ++g) {
    float s = 0.f;
#pragma unroll
    for (int r = 0; r < 8; ++r) s += bf2f(red[(g * 8 + r) * 272 + tid]);
    Cb[((size_t)((bm >> 3) + g)) * 256 + tid] = f2bf(s * 0.125f);
  }
}

// ---------------------------------------------------------------------------
__global__ void k_init(const float* __restrict__ qe, const float* __restrict__ qp,
                       const float* __restrict__ pb, float* __restrict__ queries,
                       ushort_t* __restrict__ qbf, float* __restrict__ boxes) {
  int i = blockIdx.x * 256 + threadIdx.x;
  if (i < BB * NQ * DM) {
    int rd = i % (NQ * DM);
    float v = qe[rd] + qp[rd];
    queries[i] = v;
    qbf[i] = f2bf(v);
  }
  if (i < BB * NQ * 4) boxes[i] = pb[i];
}

// ---------------------------------------------------------------------------
__global__ void k_r2ref(const float* __restrict__ h1, const float* __restrict__ w_r2,
                        const float* __restrict__ b_r2, const float* __restrict__ boxes,
                        float* __restrict__ ref) {
  int i = blockIdx.x * 256 + threadIdx.x;
  if (i >= BB * NQ * 2 * NP) return;
  int row = i >> 4, o = i & 15;
  const float* hp = h1 + (size_t)row * DM;
  const float* wp = w_r2 + (size_t)o * DM;
  float acc = b_r2[o];
  for (int k = 0; k < DM; ++k) acc += hp[k] * wp[k];
  float ro = 0.5f * tanhf(acc);
  int ax = o & 1;
  float v = boxes[row * 4 + ax] + ro;
  ref[i] = fminf(fmaxf(v, 0.f), 1.f);
}

// ---------------------------------------------------------------------------
__global__ __launch_bounds__(256) void k_attn(const float* __restrict__ qb,
                                              const float* __restrict__ kv,
                                              ushort_t* __restrict__ ao) {
  __shared__ float sc[512];
  __shared__ float qs[256];
  __shared__ float red[256];
  int row = blockIdx.x;
  int b = row / NQ;
  int tid = threadIdx.x;
  qs[tid] = qb[(size_t)row * DM + tid];
  __syncthreads();
  const float* kvb = kv + (size_t)b * NQ * DM;
  for (int k = tid; k < 512; k += 256) {
    float v = -1e30f;
    if (k < NQ) {
      const float* kp = kvb + (size_t)k * DM;
      float a = 0.f;
      for (int d = 0; d < DM; ++d) a += qs[d] * kp[d];
      v = a * (1.0f / 16.0f);
    }
    sc[k] = v;
  }
  __syncthreads();
  red[tid] = fmaxf(sc[tid], sc[tid + 256]);
  __syncthreads();
  for (int st = 128; st > 0; st >>= 1) {
    if (tid < st) red[tid] = fmaxf(red[tid], red[tid + st]);
    __syncthreads();
  }
  float mx = red[0];
  __syncthreads();
  float e0 = (tid < NQ) ? expf(sc[tid] - mx) : 0.f;
  float e1 = (tid + 256 < NQ) ? expf(sc[tid + 256] - mx) : 0.f;
  sc[tid] = e0;
  sc[tid + 256] = e1;
  red[tid] = e0 + e1;
  __syncthreads();
  for (int st = 128; st > 0; st >>= 1) {
    if (tid < st) red[tid] += red[tid + st];
    __syncthreads();
  }
  float inv = 1.0f / red[0];
  __syncthreads();
  float acc = 0.f;
  for (int k = 0; k < NQ; ++k) acc += sc[k] * kvb[(size_t)k * DM + tid];
  ao[(size_t)row * DM + tid] = f2bf(acc * inv);
}

// ---------------------------------------------------------------------------
__global__ __launch_bounds__(256) void k_box(const float* __restrict__ hb,
                                             const float* __restrict__ w_b2,
                                             const float* __restrict__ b_b2,
                                             float* __restrict__ boxes) {
  int row = blockIdx.x;
  int tid = threadIdx.x;
  int j = tid >> 6, lane = tid & 63;
  float4 hv = *(const float4*)(hb + (size_t)row * 256 + lane * 4);
  float4 wv = *(const float4*)(w_b2 + (size_t)j * 256 + lane * 4);
  float aa = hv.x * wv.x + hv.y * wv.y + hv.z * wv.z + hv.w * wv.w;
#pragma unroll
  for (int s = 32; s > 0; s >>= 1) aa += __shfl_down(aa, s, 64);
  if (lane == 0) {
    aa += b_b2[j];
    float delta = 1.0f / (1.0f + expf(-aa));
    float v = boxes[row * 4 + j] + 0.1f * tanhf(delta - 0.5f);
    boxes[row * 4 + j] = fminf(fmaxf(v, 0.f), 1.f);
  }
}

// ---------------------------------------------------------------------------
__global__ __launch_bounds__(256) void k_final(const float* __restrict__ queries,
                                               const float* __restrict__ w_cls,
                                               const float* __restrict__ b_cls,
                                               const float* __restrict__ boxes,
                                               float* __restrict__ out) {
  int row = blockIdx.x;   // 600
  int tid = threadIdx.x;
  int w = tid >> 6, lane = tid & 63;
  if (w == 0) {
    float4 qv = *(const float4*)(queries + (size_t)row * 256 + lane * 4);
    float4 wv = *(const float4*)(w_cls + lane * 4);
    float aa = qv.x * wv.x + qv.y * wv.y + qv.z * wv.z + qv.w * wv.w;
#pragma unroll
    for (int s = 32; s > 0; s >>= 1) aa += __shfl_down(aa, s, 64);
    if (lane == 0) out[row] = aa + b_cls[0];
  } else if (w == 1 && lane < 4) {
    out[600 + row * 4 + lane] = boxes[row * 4 + lane];
  }
}

// ---------------------------------------------------------------------------
extern "C" void kernel_launch(void* const* d_in, const int* in_sizes, int n_in,
                              void* d_out, int out_size, void* d_ws, size_t ws_size,
                              hipStream_t stream) {
  const float* feat   = (const float*)d_in[0];
  const float* pb     = (const float*)d_in[1];
  const float* w_tf   = (const float*)d_in[2];
  const float* b_tf   = (const float*)d_in[3];
  const float* w_in   = (const float*)d_in[4];
  const float* b_in   = (const float*)d_in[5];
  const float* w_lat  = (const float*)d_in[6];
  const float* b_lat  = (const float*)d_in[7];
  const float* w_sm   = (const float*)d_in[8];
  const float* b_sm   = (const float*)d_in[9];
  const float* q_embed= (const float*)d_in[10];
  const float* q_pos  = (const float*)d_in[11];
  const float* Wq     = (const float*)d_in[12];
  const float* bq     = (const float*)d_in[13];
  const float* Wo     = (const float*)d_in[14];
  const float* bo     = (const float*)d_in[15];
  const float* Wp1    = (const float*)d_in[16];
  const float* bp1    = (const float*)d_in[17];
  const float* Wp2    = (const float*)d_in[18];
  const float* bp2    = (const float*)d_in[19];
  const float* w_r1   = (const float*)d_in[20];
  const float* b_r1   = (const float*)d_in[21];
  const float* w_r2   = (const float*)d_in[22];
  const float* b_r2   = (const float*)d_in[23];
  const float* w_b1   = (const float*)d_in[24];
  const float* b_b1   = (const float*)d_in[25];
  const float* w_b2   = (const float*)d_in[26];
  const float* b_b2   = (const float*)d_in[27];
  const float* w_cls  = (const float*)d_in[28];
  const float* b_cls  = (const float*)d_in[29];
  float* out = (float*)d_out;

  float* ws = (float*)d_ws;
  size_t off = 0;
  auto alloc = [&](size_t n) { float* p = ws + off; off += n; return p; };
  ushort_t* xcl     = (ushort_t*)alloc(1048576);   // 8192 x 256 bf16
  ushort_t* x2p     = (ushort_t*)alloc(1115136);   // 2 x 66 x 66 x 256 bf16
  ushort_t* fcl     = (ushort_t*)alloc(1048576);   // 8192 x 256 bf16
  ushort_t* wcomb   = (ushort_t*)alloc(65536);     // 256 x 512 bf16
  ushort_t* tct     = (ushort_t*)alloc(32768);     // 512 x 128 bf16
  ushort_t* win_bf  = (ushort_t*)alloc(16384);     // 256 x 128 bf16
  float*    biasc   = alloc(256);
  ushort_t* wlat_bf = (ushort_t*)alloc(32768);
  ushort_t* wsm_bf  = (ushort_t*)alloc(294912);
  ushort_t* wp1_bf  = (ushort_t*)alloc(1769472);   // 6 x 256 x 2304
  ushort_t* wqr_bf  = (ushort_t*)alloc(393216);    // 6 x 512 x 256
  float*    bqr     = alloc(3072);                 // 6 x 512
  ushort_t* wp2_bf  = (ushort_t*)alloc(196608);    // 6 x 256 x 256
  ushort_t* wo_bf   = (ushort_t*)alloc(196608);
  ushort_t* wb1_bf  = (ushort_t*)alloc(32768);
  float* queries = alloc(153600);
  ushort_t* qbf  = (ushort_t*)alloc(76800);
  float* h1      = alloc(153600);
  float* qbuf    = alloc(153600);
  float* kv      = alloc(153600);
  ushort_t* ao   = (ushort_t*)alloc(76800);
  float* hb      = alloc(153600);
  ushort_t* pvm  = (ushort_t*)alloc(76800);
  float* boxes   = alloc(2400);
  float* ref     = alloc(9600);
  (void)ws_size; (void)in_sizes; (void)n_in; (void)out_size;

  // --- weight prep (1 mega launch + bias + wcomb GEMM + zero) ---
  k_prep<<<10029, 256, 0, stream>>>(w_in, w_lat, Wp2, Wo, w_b1, Wp1,
                                    win_bf, wlat_bf, wp2_bf, wo_bf, wb1_bf, wp1_bf,
                                    w_tf, tct, w_sm, wsm_bf, w_r1, Wq, wqr_bf,
                                    b_r1, bq, bqr);
  k_bcomb<<<1, 256, 0, stream>>>(w_in, b_tf, b_in, biasc);
  k_gemm_bf16<0, 6, 0><<<dim3(4, 8), 256, 0, stream>>>(win_bf, tct, nullptr, nullptr,
                                                       nullptr, wcomb, 256, 512, 128);
  k_zero<<<1089, 256, 0, stream>>>((uint4*)x2p, 278784);

  // --- backbone ---
  k_feat<<<dim3(128, 4), 256, 0, stream>>>(feat, wcomb, biasc, xcl);
  k_gemm_bf16<0, 1, 0><<<dim3(128, 4), 256, 0, stream>>>(xcl, wlat_bf, b_lat, nullptr,
                                                         nullptr, x2p, BB * HW, 256, 256);
  k_gemm_n256<1, 1><<<128, 256, 0, stream>>>(x2p, wsm_bf, b_sm, nullptr, fcl, BB * HW, KP);
  k_init<<<600, 256, 0, stream>>>(q_embed, q_pos, pb, queries, qbf, boxes);

  const int M6 = BB * NQ;                 // 600
  dim3 g600((M6 + 63) / 64, 4);           // (10,4)
  dim3 g600w((M6 + 63) / 64, 8);          // (10,8) for merged N=512

  for (int l = 0; l < NL; ++l) {
    // merged h1 (relu) | qbuf GEMM on queries
    k_gemm_bf16<0, 4, 1><<<g600w, 256, 0, stream>>>(qbf, wqr_bf + (size_t)l * 512 * 256,
                                                    bqr + l * 512, nullptr, h1,
                                                    (ushort_t*)qbuf, M6, 512, 256);
    k_r2ref<<<(M6 * 16 + 255) / 256, 256, 0, stream>>>(h1, w_r2, b_r2, boxes, ref);
    // Wp1 GEMM with FUSED bilinear sampling + relu + pmean -> pvm bf16
    k_gemm_n256<2, 0><<<75, 256, 0, stream>>>(fcl, wp1_bf + (size_t)l * 256 * KP,
                                              bp1 + (size_t)l * DM, ref, pvm,
                                              BB * NQ * NP, KP);
    // kv = pvm @ Wp2 + bp2
    k_gemm_bf16<0, 0, 1><<<g600, 256, 0, stream>>>(pvm, wp2_bf + (size_t)l * DM * DM,
                                                   bp2 + (size_t)l * DM, nullptr, kv,
                                                   nullptr, M6, DM, DM);
    k_attn<<<M6, 256, 0, stream>>>(qbuf, kv, ao);
    // queries += ao @ Wo + bo   (fp32 master + bf16 mirror)
    k_gemm_bf16<0, 2, 1><<<g600, 256, 0, stream>>>(ao, wo_bf + (size_t)l * DM * DM,
                                                   bo + (size_t)l * DM, queries, queries,
                                                   qbf, M6, DM, DM);
    // hb = relu(queries @ w_b1 + b_b1)
    k_gemm_bf16<1, 0, 1><<<g600, 256, 0, stream>>>(qbf, wb1_bf, b_b1, nullptr, hb,
                                                   nullptr, M6, DM, DM);
    k_box<<<M6, 256, 0, stream>>>(hb, w_b2, b_b2, boxes);
  }
  k_final<<<M6, 256, 0, stream>>>(queries, w_cls, b_cls, boxes, out);
}

// Round 7
// 847.226 us; speedup vs baseline: 2.2316x; 2.2316x over previous
//
#include <hip/hip_runtime.h>
#include <hip/hip_bf16.h>
#include <math.h>

// Problem constants
#define BB 2
#define TT 4
#define CIN 128
#define DM 256
#define NQ 300
#define NP 8
#define PS 3
#define NL 6
#define HW 4096   // 64*64
#define KP 2304   // 3*3*256

typedef __attribute__((ext_vector_type(8))) short short8;
typedef __attribute__((ext_vector_type(4))) float f32x4;
typedef unsigned short ushort_t;

static __device__ __forceinline__ ushort_t f2bf(float f) {
  __hip_bfloat16 h = __float2bfloat16(f);
  return *reinterpret_cast<ushort_t*>(&h);
}
static __device__ __forceinline__ float bf2f(ushort_t u) {
  return __uint_as_float(((unsigned)u) << 16);
}

// ---------------------------------------------------------------------------
// ONE mega weight-prep kernel (block-range ladder).
__global__ void k_prep(const float* __restrict__ w_in, const float* __restrict__ w_lat,
                       const float* __restrict__ Wp2, const float* __restrict__ Wo,
                       const float* __restrict__ w_b1, const float* __restrict__ Wp1,
                       ushort_t* __restrict__ win_bf, ushort_t* __restrict__ wlat_bf,
                       ushort_t* __restrict__ wp2_bf, ushort_t* __restrict__ wo_bf,
                       ushort_t* __restrict__ wb1_bf, ushort_t* __restrict__ wp1_bf,
                       const float* __restrict__ w_tf, ushort_t* __restrict__ tct,
                       const float* __restrict__ w_sm, ushort_t* __restrict__ wsm_bf,
                       const float* __restrict__ w_r1, const float* __restrict__ Wq,
                       ushort_t* __restrict__ wqr_bf,
                       const float* __restrict__ b_r1, const float* __restrict__ bq,
                       float* __restrict__ bqr) {
  int b = blockIdx.x, t = threadIdx.x;
  if (b < 4385) {
    int i = b * 256 + t;
    const float* s; ushort_t* d; int base;
    if (i < 8192)         { s = w_in;  d = win_bf;  base = 0; }
    else if (i < 24576)   { s = w_lat; d = wlat_bf; base = 8192; }
    else if (i < 122880)  { s = Wp2;   d = wp2_bf;  base = 24576; }
    else if (i < 221184)  { s = Wo;    d = wo_bf;   base = 122880; }
    else if (i < 237568)  { s = w_b1;  d = wb1_bf;  base = 221184; }
    else if (i < 1122304) { s = Wp1;   d = wp1_bf;  base = 237568; }
    else return;
    int j = i - base;
    float4 v = ((const float4*)s)[j];
    d[j * 4 + 0] = f2bf(v.x);
    d[j * 4 + 1] = f2bf(v.y);
    d[j * 4 + 2] = f2bf(v.z);
    d[j * 4 + 3] = f2bf(v.w);
  } else if (b < 4641) {
    int i = (b - 4385) * 256 + t;     // < 512*128
    int k = i >> 7, c = i & 127;
    int u = k >> 7, ci = k & 127;
    const float* wp = w_tf + ((size_t)(c * 128 + ci)) * 3;
    float w0 = wp[0], w1 = wp[1], w2 = wp[2];
    float coef = (u == 0) ? (w0 + w1) : (u == 3) ? (w1 + w2) : (w0 + w1 + w2);
    tct[(size_t)k * 128 + c] = f2bf(0.25f * coef);
  } else if (b < 6945) {
    int i = (b - 4641) * 256 + t;     // < 256*2304
    int n = i / KP;
    int r = i - n * KP;
    int tp = r >> 8, c = r & 255;
    wsm_bf[i] = f2bf(w_sm[((size_t)(n * 256 + c)) * 9 + tp]);
  } else if (b < 10017) {
    int i = (b - 6945) * 256 + t;     // < 6*512*256
    int l = i / (512 * 256);
    int r = i - l * 512 * 256;
    int n = r >> 8, c = r & 255;
    float v = (n < 256) ? w_r1[n * 256 + c] : Wq[((size_t)l * 256 + (n - 256)) * 256 + c];
    wqr_bf[i] = f2bf(v);
  } else {
    int i = (b - 10017) * 256 + t;    // < 6*512
    if (i >= NL * 512) return;
    int l = i >> 9, n = i & 511;
    bqr[i] = (n < 256) ? b_r1[n] : bq[l * 256 + n - 256];
  }
}

// bias_comb[d] = b_in[d] + sum_c w_in[d,c]*b_tf[c]
__global__ void k_bcomb(const float* __restrict__ w_in, const float* __restrict__ b_tf,
                        const float* __restrict__ b_in, float* __restrict__ bias_comb) {
  __shared__ float bt[128];
  int d = threadIdx.x;
  if (d < 128) bt[d] = b_tf[d];
  __syncthreads();
  float a = b_in[d];
  for (int c = 0; c < 128; ++c) a += w_in[d * 128 + c] * bt[c];
  bias_comb[d] = a;
}

// ---------------------------------------------------------------------------
// Fused backbone GEMM: xcl = bf16(feat_t . Wcomb + bias + pos)
__global__ __launch_bounds__(256) void k_feat(const float* __restrict__ feat,
                                              const ushort_t* __restrict__ wcomb,
                                              const float* __restrict__ bias_comb,
                                              ushort_t* __restrict__ xcl) {
  __shared__ ushort_t As[64 * 36];
  __shared__ ushort_t Bs[64 * 36];
  __shared__ float dimt_s[256];
  int tid = threadIdx.x;
  {
    int dd = tid & 127;
    int ii = dd >> 1;
    float e = (2.0f * (float)(ii >> 1)) / 64.0f;
    dimt_s[tid] = powf(10000.0f, e);
  }
  int bm = blockIdx.x * 64, bn = blockIdx.y * 64;
  int b = bm >> 12;
  int s0 = bm & 4095;
  int w = tid >> 6, lane = tid & 63;
  int wm = (w & 1) * 32, wn = (w >> 1) * 32;
  int q = lane >> 4, ml = lane & 15;
  int srow = tid >> 2, scol = (tid & 3) * 8;
  const ushort_t* Wg = wcomb + (size_t)(bn + srow) * 512 + scol;
  f32x4 acc[2][2] = {};
  for (int k0 = 0; k0 < 512; k0 += 32) {
    short8 wv = *(const short8*)(Wg + k0);
#pragma unroll
    for (int j = 0; j < 8; ++j) {
      int kk = w * 8 + j;
      int k = k0 + kk;
      int u = k >> 7, ci = k & 127;
      float v = feat[(((size_t)(b * 4 + u) * 128 + ci) << 12) + s0 + lane];
      As[lane * 36 + kk] = f2bf(v);
    }
    *(short8*)(Bs + srow * 36 + scol) = wv;
    __syncthreads();
    short8 a0 = *(const short8*)(As + (wm + ml) * 36 + q * 8);
    short8 a1 = *(const short8*)(As + (wm + 16 + ml) * 36 + q * 8);
    short8 b0 = *(const short8*)(Bs + (wn + ml) * 36 + q * 8);
    short8 b1 = *(const short8*)(Bs + (wn + 16 + ml) * 36 + q * 8);
    acc[0][0] = __builtin_amdgcn_mfma_f32_16x16x32_bf16(a0, b0, acc[0][0], 0, 0, 0);
    acc[0][1] = __builtin_amdgcn_mfma_f32_16x16x32_bf16(a0, b1, acc[0][1], 0, 0, 0);
    acc[1][0] = __builtin_amdgcn_mfma_f32_16x16x32_bf16(a1, b0, acc[1][0], 0, 0, 0);
    acc[1][1] = __builtin_amdgcn_mfma_f32_16x16x32_bf16(a1, b1, acc[1][1], 0, 0, 0);
    __syncthreads();
  }
  const float FKT = 6.28318530717958647692f / 64.000001f;
#pragma unroll
  for (int i2 = 0; i2 < 2; ++i2) {
#pragma unroll
    for (int j2 = 0; j2 < 2; ++j2) {
      int cn = bn + wn + j2 * 16 + ml;
      float dimt = dimt_s[cn];
      float bC = bias_comb[cn];
      bool isx = cn >= 128;
      bool isc = cn & 1;
#pragma unroll
      for (int r = 0; r < 4; ++r) {
        int rm = bm + wm + i2 * 16 + q * 4 + r;
        int s = rm & 4095;
        int y = s >> 6, x = s & 63;
        float ang = (float)((isx ? x : y) + 1) * FKT / dimt;
        float pos = isc ? cosf(ang) : sinf(ang);
        xcl[(size_t)rm * 256 + cn] = f2bf(acc[i2][j2][r] + bC + pos);
      }
    }
  }
}

// ---------------------------------------------------------------------------
__global__ void k_zero(uint4* __restrict__ p, int n) {
  int i = blockIdx.x * 256 + threadIdx.x;
  if (i < n) p[i] = make_uint4(0u, 0u, 0u, 0u);
}

// ---------------------------------------------------------------------------
// bf16 MFMA GEMM, BM=BN=64, BK=32.
// OUTMODE: 0 = fp32 C (bias+ACT); 1 = bf16 padded (B,66,66,256);
//          2 = fp32 C + bf16 mirror + residual; 4 = split relu|fp32 (N=512);
//          6 = plain bf16 out
template <int ACT, int OUTMODE, int MG>
__global__ __launch_bounds__(256) void k_gemm_bf16(const ushort_t* __restrict__ A,
                                                   const ushort_t* __restrict__ W,
                                                   const float* __restrict__ bias,
                                                   const float* __restrict__ res,
                                                   float* __restrict__ Cf,
                                                   ushort_t* __restrict__ Cb,
                                                   int M, int N, int K) {
  __shared__ ushort_t As[64 * 36];
  __shared__ ushort_t Bs[64 * 36];
  int tid = threadIdx.x;
  int bm = blockIdx.x * 64, bn = blockIdx.y * 64;
  int w = tid >> 6, lane = tid & 63;
  int wm = (w & 1) * 32, wn = (w >> 1) * 32;
  int q = lane >> 4, ml = lane & 15;
  f32x4 acc[2][2] = {};
  int srow = tid >> 2, scol = (tid & 3) * 8;
  int ga = bm + srow;
  if (MG) ga = min(ga, M - 1);
  const ushort_t* Ag = A + (size_t)ga * K + scol;
  const ushort_t* Wg = W + (size_t)(bn + srow) * K + scol;
  for (int k0 = 0; k0 < K; k0 += 32) {
    short8 av = *(const short8*)(Ag + k0);
    short8 wv = *(const short8*)(Wg + k0);
    *(short8*)(As + srow * 36 + scol) = av;
    *(short8*)(Bs + srow * 36 + scol) = wv;
    __syncthreads();
    short8 a0 = *(const short8*)(As + (wm + ml) * 36 + q * 8);
    short8 a1 = *(const short8*)(As + (wm + 16 + ml) * 36 + q * 8);
    short8 b0 = *(const short8*)(Bs + (wn + ml) * 36 + q * 8);
    short8 b1 = *(const short8*)(Bs + (wn + 16 + ml) * 36 + q * 8);
    acc[0][0] = __builtin_amdgcn_mfma_f32_16x16x32_bf16(a0, b0, acc[0][0], 0, 0, 0);
    acc[0][1] = __builtin_amdgcn_mfma_f32_16x16x32_bf16(a0, b1, acc[0][1], 0, 0, 0);
    acc[1][0] = __builtin_amdgcn_mfma_f32_16x16x32_bf16(a1, b0, acc[1][0], 0, 0, 0);
    acc[1][1] = __builtin_amdgcn_mfma_f32_16x16x32_bf16(a1, b1, acc[1][1], 0, 0, 0);
    __syncthreads();
  }
#pragma unroll
  for (int i = 0; i < 2; ++i) {
#pragma unroll
    for (int j = 0; j < 2; ++j) {
      int cn = bn + wn + j * 16 + ml;
      float bsv = bias ? bias[cn] : 0.f;
#pragma unroll
      for (int r = 0; r < 4; ++r) {
        int rm = bm + wm + i * 16 + q * 4 + r;
        if (MG && rm >= M) continue;
        float v = acc[i][j][r] + bsv;
        if (OUTMODE == 0) {
          if (ACT == 1) v = fmaxf(v, 0.f);
          Cf[(size_t)rm * N + cn] = v;
        } else if (OUTMODE == 1) {
          int b = rm >> 12, rem = rm & 4095;
          int y = rem >> 6, xx = rem & 63;
          Cb[(((size_t)(b * 66 + y + 1)) * 66 + xx + 1) * 256 + cn] = f2bf(v);
        } else if (OUTMODE == 2) {
          v += res[(size_t)rm * N + cn];
          Cf[(size_t)rm * N + cn] = v;
          Cb[(size_t)rm * N + cn] = f2bf(v);
        } else if (OUTMODE == 4) {
          if (cn < 256) Cf[(size_t)rm * 256 + cn] = fmaxf(v, 0.f);
          else ((float*)Cb)[(size_t)rm * 256 + cn - 256] = v;
        } else if (OUTMODE == 6) {
          Cb[(size_t)rm * N + cn] = f2bf(v);
        }
      }
    }
  }
}

// ---------------------------------------------------------------------------
// Wp1 split-K phase 1: C_part[z] = flat[:, z*768:(z+1)*768] @ Wp1_chunk^T
// grid (75, 4, 3), 64x64 tile, register-prefetched K-loop (24 iters).
__global__ __launch_bounds__(256) void k_wp1_split(const ushort_t* __restrict__ A,
                                                   const ushort_t* __restrict__ W,
                                                   float* __restrict__ part) {
  __shared__ ushort_t As[64 * 36];
  __shared__ ushort_t Bs[64 * 36];
  int tid = threadIdx.x;
  int bm = blockIdx.x * 64, bn = blockIdx.y * 64;
  int kz = blockIdx.z * 768;
  int w = tid >> 6, lane = tid & 63;
  int wm = (w & 1) * 32, wn = (w >> 1) * 32;
  int q = lane >> 4, ml = lane & 15;
  int srow = tid >> 2, scol = (tid & 3) * 8;
  const ushort_t* Ag = A + (size_t)(bm + srow) * KP + kz + scol;
  const ushort_t* Wg = W + (size_t)(bn + srow) * KP + kz + scol;
  f32x4 acc[2][2] = {};
  short8 av = *(const short8*)(Ag);
  short8 wv = *(const short8*)(Wg);
  for (int k0 = 0; k0 < 768; k0 += 32) {
    *(short8*)(As + srow * 36 + scol) = av;
    *(short8*)(Bs + srow * 36 + scol) = wv;
    __syncthreads();
    if (k0 + 32 < 768) {
      av = *(const short8*)(Ag + k0 + 32);
      wv = *(const short8*)(Wg + k0 + 32);
    }
    short8 a0 = *(const short8*)(As + (wm + ml) * 36 + q * 8);
    short8 a1 = *(const short8*)(As + (wm + 16 + ml) * 36 + q * 8);
    short8 b0 = *(const short8*)(Bs + (wn + ml) * 36 + q * 8);
    short8 b1 = *(const short8*)(Bs + (wn + 16 + ml) * 36 + q * 8);
    acc[0][0] = __builtin_amdgcn_mfma_f32_16x16x32_bf16(a0, b0, acc[0][0], 0, 0, 0);
    acc[0][1] = __builtin_amdgcn_mfma_f32_16x16x32_bf16(a0, b1, acc[0][1], 0, 0, 0);
    acc[1][0] = __builtin_amdgcn_mfma_f32_16x16x32_bf16(a1, b0, acc[1][0], 0, 0, 0);
    acc[1][1] = __builtin_amdgcn_mfma_f32_16x16x32_bf16(a1, b1, acc[1][1], 0, 0, 0);
    __syncthreads();
  }
  float* pz = part + (size_t)blockIdx.z * 4800 * 256;
#pragma unroll
  for (int i = 0; i < 2; ++i)
#pragma unroll
    for (int j = 0; j < 2; ++j) {
      int cn = bn + wn + j * 16 + ml;
#pragma unroll
      for (int r = 0; r < 4; ++r) {
        int rm = bm + wm + i * 16 + q * 4 + r;
        pz[(size_t)rm * 256 + cn] = acc[i][j][r];
      }
    }
}

// Wp1 split-K phase 2: pvm[row][d] = bf16( mean_p relu( sum_z part + bias ) )
__global__ __launch_bounds__(256) void k_wp1_reduce(const float* __restrict__ part,
                                                    const float* __restrict__ bias,
                                                    ushort_t* __restrict__ pvm) {
  int row = blockIdx.x;   // 600
  int d = threadIdx.x;
  float b = bias[d];
  float s = 0.f;
#pragma unroll
  for (int p = 0; p < 8; ++p) {
    size_t idx = (size_t)(row * 8 + p) * 256 + d;
    float v = part[idx] + part[idx + (size_t)4800 * 256] +
              part[idx + (size_t)2 * 4800 * 256] + b;
    s += fmaxf(v, 0.f);
  }
  pvm[(size_t)row * 256 + d] = f2bf(s * 0.125f);
}

// ---------------------------------------------------------------------------
// 3x3 conv as GEMM, A gathered from padded x2p; 64x64 tiles, grid (128,4),
// register-prefetched 72-iter K-loop. Writes fcl bf16 channel-last.
__global__ __launch_bounds__(256) void k_conv3(const ushort_t* __restrict__ x2p,
                                               const ushort_t* __restrict__ wsm,
                                               const float* __restrict__ bsm,
                                               ushort_t* __restrict__ fcl) {
  __shared__ ushort_t As[64 * 36];
  __shared__ ushort_t Bs[64 * 36];
  int tid = threadIdx.x;
  int bm = blockIdx.x * 64, bn = blockIdx.y * 64;
  int w = tid >> 6, lane = tid & 63;
  int wm = (w & 1) * 32, wn = (w >> 1) * 32;
  int q = lane >> 4, ml = lane & 15;
  int srow = tid >> 2, scol = (tid & 3) * 8;
  int sA = bm + srow;
  int b = sA >> 12, rem = sA & 4095;
  size_t pbase = ((size_t)(b * 66 + (rem >> 6)) * 66 + (rem & 63)) * 256;
  const ushort_t* Wg = wsm + (size_t)(bn + srow) * KP + scol;
  auto loadA = [&](int k0) {
    int ka = k0 + scol;
    int t9 = ka >> 8;
    int ky = t9 / 3, kx = t9 - ky * 3;
    return *(const short8*)(x2p + pbase + (size_t)(ky * 66 + kx) * 256 + (ka & 255));
  };
  f32x4 acc[2][2] = {};
  short8 av = loadA(0);
  short8 wv = *(const short8*)(Wg);
  for (int k0 = 0; k0 < KP; k0 += 32) {
    *(short8*)(As + srow * 36 + scol) = av;
    *(short8*)(Bs + srow * 36 + scol) = wv;
    __syncthreads();
    if (k0 + 32 < KP) {
      av = loadA(k0 + 32);
      wv = *(const short8*)(Wg + k0 + 32);
    }
    short8 a0 = *(const short8*)(As + (wm + ml) * 36 + q * 8);
    short8 a1 = *(const short8*)(As + (wm + 16 + ml) * 36 + q * 8);
    short8 b0 = *(const short8*)(Bs + (wn + ml) * 36 + q * 8);
    short8 b1 = *(const short8*)(Bs + (wn + 16 + ml) * 36 + q * 8);
    acc[0][0] = __builtin_amdgcn_mfma_f32_16x16x32_bf16(a0, b0, acc[0][0], 0, 0, 0);
    acc[0][1] = __builtin_amdgcn_mfma_f32_16x16x32_bf16(a0, b1, acc[0][1], 0, 0, 0);
    acc[1][0] = __builtin_amdgcn_mfma_f32_16x16x32_bf16(a1, b0, acc[1][0], 0, 0, 0);
    acc[1][1] = __builtin_amdgcn_mfma_f32_16x16x32_bf16(a1, b1, acc[1][1], 0, 0, 0);
    __syncthreads();
  }
#pragma unroll
  for (int i = 0; i < 2; ++i)
#pragma unroll
    for (int j = 0; j < 2; ++j) {
      int cn = bn + wn + j * 16 + ml;
      float bsv = bsm[cn];
#pragma unroll
      for (int r = 0; r < 4; ++r) {
        int rm = bm + wm + i * 16 + q * 4 + r;
        fcl[(size_t)rm * 256 + cn] = f2bf(acc[i][j][r] + bsv);
      }
    }
}

// ---------------------------------------------------------------------------
__global__ void k_init(const float* __restrict__ qe, const float* __restrict__ qp,
                       const float* __restrict__ pb, float* __restrict__ queries,
                       ushort_t* __restrict__ qbf, float* __restrict__ boxes) {
  int i = blockIdx.x * 256 + threadIdx.x;
  if (i < BB * NQ * DM) {
    int rd = i % (NQ * DM);
    float v = qe[rd] + qp[rd];
    queries[i] = v;
    qbf[i] = f2bf(v);
  }
  if (i < BB * NQ * 4) boxes[i] = pb[i];
}

// ---------------------------------------------------------------------------
// Fused r2ref + bilinear patch sampling. Block per (b,q,p); thread = channel.
__global__ __launch_bounds__(256) void k_sample(const ushort_t* __restrict__ fcl,
                                                const float* __restrict__ h1,
                                                const float* __restrict__ w_r2,
                                                const float* __restrict__ b_r2,
                                                const float* __restrict__ boxes,
                                                ushort_t* __restrict__ flat) {
  __shared__ float pr[8];
  __shared__ float bc2[2];
  int blk = blockIdx.x;             // (b*NQ+q)*NP + p
  int row = blk >> 3, p = blk & 7;
  int b = row / NQ;
  int tid = threadIdx.x;
  float h = h1[(size_t)row * 256 + tid];
  float px = h * w_r2[(size_t)(2 * p) * 256 + tid];
  float py = h * w_r2[(size_t)(2 * p + 1) * 256 + tid];
#pragma unroll
  for (int s = 32; s > 0; s >>= 1) {
    px += __shfl_down(px, s, 64);
    py += __shfl_down(py, s, 64);
  }
  int w = tid >> 6, lane = tid & 63;
  if (lane == 0) { pr[w * 2] = px; pr[w * 2 + 1] = py; }
  __syncthreads();
  if (tid == 0) {
    float sx = pr[0] + pr[2] + pr[4] + pr[6] + b_r2[2 * p];
    float sy = pr[1] + pr[3] + pr[5] + pr[7] + b_r2[2 * p + 1];
    float rx = boxes[row * 4 + 0] + 0.5f * tanhf(sx);
    float ry = boxes[row * 4 + 1] + 0.5f * tanhf(sy);
    bc2[0] = fminf(fmaxf(rx, 0.f), 1.f);
    bc2[1] = fminf(fmaxf(ry, 0.f), 1.f);
  }
  __syncthreads();
  float rx = bc2[0], ry = bc2[1];
  int c = tid;
  const ushort_t* fb = fcl + (size_t)b * HW * DM;
  ushort_t* op = flat + (size_t)blk * KP;
#pragma unroll
  for (int jy = 0; jy < 3; ++jy) {
    float yy = (ry + (float)(jy - 1) * (1.0f / 64.0f)) * 63.0f;
    yy = fminf(fmaxf(yy, 0.f), 63.0f);
    float y0f = floorf(yy);
    float wy = yy - y0f;
    int y0 = (int)y0f;
    int y1 = min(y0 + 1, 63);
#pragma unroll
    for (int jx = 0; jx < 3; ++jx) {
      float xx = (rx + (float)(jx - 1) * (1.0f / 64.0f)) * 63.0f;
      xx = fminf(fmaxf(xx, 0.f), 63.0f);
      float x0f = floorf(xx);
      float wx = xx - x0f;
      int x0 = (int)x0f;
      int x1 = min(x0 + 1, 63);
      float v00 = bf2f(fb[(y0 * 64 + x0) * DM + c]);
      float v01 = bf2f(fb[(y0 * 64 + x1) * DM + c]);
      float v10 = bf2f(fb[(y1 * 64 + x0) * DM + c]);
      float v11 = bf2f(fb[(y1 * 64 + x1) * DM + c]);
      float v = v00 * (1.f - wx) * (1.f - wy) + v01 * wx * (1.f - wy) +
                v10 * (1.f - wx) * wy + v11 * wx * wy;
      op[(jy * 3 + jx) * DM + c] = f2bf(v);
    }
  }
}

// ---------------------------------------------------------------------------
__global__ __launch_bounds__(256) void k_attn(const float* __restrict__ qb,
                                              const float* __restrict__ kv,
                                              ushort_t* __restrict__ ao) {
  __shared__ float sc[512];
  __shared__ float qs[256];
  __shared__ float red[256];
  int row = blockIdx.x;
  int b = row / NQ;
  int tid = threadIdx.x;
  qs[tid] = qb[(size_t)row * DM + tid];
  __syncthreads();
  const float* kvb = kv + (size_t)b * NQ * DM;
  for (int k = tid; k < 512; k += 256) {
    float v = -1e30f;
    if (k < NQ) {
      const float* kp = kvb + (size_t)k * DM;
      float a = 0.f;
      for (int d = 0; d < DM; ++d) a += qs[d] * kp[d];
      v = a * (1.0f / 16.0f);
    }
    sc[k] = v;
  }
  __syncthreads();
  red[tid] = fmaxf(sc[tid], sc[tid + 256]);
  __syncthreads();
  for (int st = 128; st > 0; st >>= 1) {
    if (tid < st) red[tid] = fmaxf(red[tid], red[tid + st]);
    __syncthreads();
  }
  float mx = red[0];
  __syncthreads();
  float e0 = (tid < NQ) ? expf(sc[tid] - mx) : 0.f;
  float e1 = (tid + 256 < NQ) ? expf(sc[tid + 256] - mx) : 0.f;
  sc[tid] = e0;
  sc[tid + 256] = e1;
  red[tid] = e0 + e1;
  __syncthreads();
  for (int st = 128; st > 0; st >>= 1) {
    if (tid < st) red[tid] += red[tid + st];
    __syncthreads();
  }
  float inv = 1.0f / red[0];
  __syncthreads();
  float acc = 0.f;
  for (int k = 0; k < NQ; ++k) acc += sc[k] * kvb[(size_t)k * DM + tid];
  ao[(size_t)row * DM + tid] = f2bf(acc * inv);
}

// ---------------------------------------------------------------------------
__global__ __launch_bounds__(256) void k_box(const float* __restrict__ hb,
                                             const float* __restrict__ w_b2,
                                             const float* __restrict__ b_b2,
                                             float* __restrict__ boxes) {
  int row = blockIdx.x;
  int tid = threadIdx.x;
  int j = tid >> 6, lane = tid & 63;
  float4 hv = *(const float4*)(hb + (size_t)row * 256 + lane * 4);
  float4 wv = *(const float4*)(w_b2 + (size_t)j * 256 + lane * 4);
  float aa = hv.x * wv.x + hv.y * wv.y + hv.z * wv.z + hv.w * wv.w;
#pragma unroll
  for (int s = 32; s > 0; s >>= 1) aa += __shfl_down(aa, s, 64);
  if (lane == 0) {
    aa += b_b2[j];
    float delta = 1.0f / (1.0f + expf(-aa));
    float v = boxes[row * 4 + j] + 0.1f * tanhf(delta - 0.5f);
    boxes[row * 4 + j] = fminf(fmaxf(v, 0.f), 1.f);
  }
}

// ---------------------------------------------------------------------------
__global__ __launch_bounds__(256) void k_final(const float* __restrict__ queries,
                                               const float* __restrict__ w_cls,
                                               const float* __restrict__ b_cls,
                                               const float* __restrict__ boxes,
                                               float* __restrict__ out) {
  int row = blockIdx.x;   // 600
  int tid = threadIdx.x;
  int w = tid >> 6, lane = tid & 63;
  if (w == 0) {
    float4 qv = *(const float4*)(queries + (size_t)row * 256 + lane * 4);
    float4 wv = *(const float4*)(w_cls + lane * 4);
    float aa = qv.x * wv.x + qv.y * wv.y + qv.z * wv.z + qv.w * wv.w;
#pragma unroll
    for (int s = 32; s > 0; s >>= 1) aa += __shfl_down(aa, s, 64);
    if (lane == 0) out[row] = aa + b_cls[0];
  } else if (w == 1 && lane < 4) {
    out[600 + row * 4 + lane] = boxes[row * 4 + lane];
  }
}

// ---------------------------------------------------------------------------
extern "C" void kernel_launch(void* const* d_in, const int* in_sizes, int n_in,
                              void* d_out, int out_size, void* d_ws, size_t ws_size,
                              hipStream_t stream) {
  const float* feat   = (const float*)d_in[0];
  const float* pb     = (const float*)d_in[1];
  const float* w_tf   = (const float*)d_in[2];
  const float* b_tf   = (const float*)d_in[3];
  const float* w_in   = (const float*)d_in[4];
  const float* b_in   = (const float*)d_in[5];
  const float* w_lat  = (const float*)d_in[6];
  const float* b_lat  = (const float*)d_in[7];
  const float* w_sm   = (const float*)d_in[8];
  const float* b_sm   = (const float*)d_in[9];
  const float* q_embed= (const float*)d_in[10];
  const float* q_pos  = (const float*)d_in[11];
  const float* Wq     = (const float*)d_in[12];
  const float* bq     = (const float*)d_in[13];
  const float* Wo     = (const float*)d_in[14];
  const float* bo     = (const float*)d_in[15];
  const float* Wp1    = (const float*)d_in[16];
  const float* bp1    = (const float*)d_in[17];
  const float* Wp2    = (const float*)d_in[18];
  const float* bp2    = (const float*)d_in[19];
  const float* w_r1   = (const float*)d_in[20];
  const float* b_r1   = (const float*)d_in[21];
  const float* w_r2   = (const float*)d_in[22];
  const float* b_r2   = (const float*)d_in[23];
  const float* w_b1   = (const float*)d_in[24];
  const float* b_b1   = (const float*)d_in[25];
  const float* w_b2   = (const float*)d_in[26];
  const float* b_b2   = (const float*)d_in[27];
  const float* w_cls  = (const float*)d_in[28];
  const float* b_cls  = (const float*)d_in[29];
  float* out = (float*)d_out;

  float* ws = (float*)d_ws;
  size_t off = 0;
  auto alloc = [&](size_t n) { float* p = ws + off; off += n; return p; };
  ushort_t* flat    = (ushort_t*)alloc(5529600);   // 4800 x 2304 bf16
  float*    part    = alloc(3686400);              // 3 x 4800 x 256 fp32
  ushort_t* xcl     = (ushort_t*)alloc(1048576);   // 8192 x 256 bf16
  ushort_t* x2p     = (ushort_t*)alloc(1115136);   // 2 x 66 x 66 x 256 bf16
  ushort_t* fcl     = (ushort_t*)alloc(1048576);   // 8192 x 256 bf16
  ushort_t* wcomb   = (ushort_t*)alloc(65536);     // 256 x 512 bf16
  ushort_t* tct     = (ushort_t*)alloc(32768);     // 512 x 128 bf16
  ushort_t* win_bf  = (ushort_t*)alloc(16384);     // 256 x 128 bf16
  float*    biasc   = alloc(256);
  ushort_t* wlat_bf = (ushort_t*)alloc(32768);
  ushort_t* wsm_bf  = (ushort_t*)alloc(294912);
  ushort_t* wp1_bf  = (ushort_t*)alloc(1769472);   // 6 x 256 x 2304
  ushort_t* wqr_bf  = (ushort_t*)alloc(393216);    // 6 x 512 x 256
  float*    bqr     = alloc(3072);                 // 6 x 512
  ushort_t* wp2_bf  = (ushort_t*)alloc(196608);    // 6 x 256 x 256
  ushort_t* wo_bf   = (ushort_t*)alloc(196608);
  ushort_t* wb1_bf  = (ushort_t*)alloc(32768);
  float* queries = alloc(153600);
  ushort_t* qbf  = (ushort_t*)alloc(76800);
  float* h1      = alloc(153600);
  float* qbuf    = alloc(153600);
  float* kv      = alloc(153600);
  ushort_t* ao   = (ushort_t*)alloc(76800);
  float* hb      = alloc(153600);
  ushort_t* pvm  = (ushort_t*)alloc(76800);
  float* boxes   = alloc(2400);
  (void)ws_size; (void)in_sizes; (void)n_in; (void)out_size;

  // --- weight prep ---
  k_prep<<<10029, 256, 0, stream>>>(w_in, w_lat, Wp2, Wo, w_b1, Wp1,
                                    win_bf, wlat_bf, wp2_bf, wo_bf, wb1_bf, wp1_bf,
                                    w_tf, tct, w_sm, wsm_bf, w_r1, Wq, wqr_bf,
                                    b_r1, bq, bqr);
  k_bcomb<<<1, 256, 0, stream>>>(w_in, b_tf, b_in, biasc);
  k_gemm_bf16<0, 6, 0><<<dim3(4, 8), 256, 0, stream>>>(win_bf, tct, nullptr, nullptr,
                                                       nullptr, wcomb, 256, 512, 128);
  k_zero<<<1089, 256, 0, stream>>>((uint4*)x2p, 278784);

  // --- backbone ---
  k_feat<<<dim3(128, 4), 256, 0, stream>>>(feat, wcomb, biasc, xcl);
  k_gemm_bf16<0, 1, 0><<<dim3(128, 4), 256, 0, stream>>>(xcl, wlat_bf, b_lat, nullptr,
                                                         nullptr, x2p, BB * HW, 256, 256);
  k_conv3<<<dim3(128, 4), 256, 0, stream>>>(x2p, wsm_bf, b_sm, fcl);
  k_init<<<600, 256, 0, stream>>>(q_embed, q_pos, pb, queries, qbf, boxes);

  const int M6 = BB * NQ;                 // 600
  const int Mp = BB * NQ * NP;            // 4800
  dim3 g600((M6 + 63) / 64, 4);           // (10,4)
  dim3 g600w((M6 + 63) / 64, 8);          // (10,8) for merged N=512
  dim3 gsk(Mp / 64, 4, 3);                // (75,4,3) split-K

  for (int l = 0; l < NL; ++l) {
    // merged h1 (relu) | qbuf GEMM on queries
    k_gemm_bf16<0, 4, 1><<<g600w, 256, 0, stream>>>(qbf, wqr_bf + (size_t)l * 512 * 256,
                                                    bqr + l * 512, nullptr, h1,
                                                    (ushort_t*)qbuf, M6, 512, 256);
    // fused ref-point + sampling -> flat
    k_sample<<<Mp, 256, 0, stream>>>(fcl, h1, w_r2, b_r2, boxes, flat);
    // Wp1: split-K x3 + reduce(relu+pmean) -> pvm
    k_wp1_split<<<gsk, 256, 0, stream>>>(flat, wp1_bf + (size_t)l * 256 * KP, part);
    k_wp1_reduce<<<600, 256, 0, stream>>>(part, bp1 + (size_t)l * DM, pvm);
    // kv = pvm @ Wp2 + bp2
    k_gemm_bf16<0, 0, 1><<<g600, 256, 0, stream>>>(pvm, wp2_bf + (size_t)l * DM * DM,
                                                   bp2 + (size_t)l * DM, nullptr, kv,
                                                   nullptr, M6, DM, DM);
    k_attn<<<M6, 256, 0, stream>>>(qbuf, kv, ao);
    // queries += ao @ Wo + bo   (fp32 master + bf16 mirror)
    k_gemm_bf16<0, 2, 1><<<g600, 256, 0, stream>>>(ao, wo_bf + (size_t)l * DM * DM,
                                                   bo + (size_t)l * DM, queries, queries,
                                                   qbf, M6, DM, DM);
    // hb = relu(queries @ w_b1 + b_b1)
    k_gemm_bf16<1, 0, 1><<<g600, 256, 0, stream>>>(qbf, wb1_bf, b_b1, nullptr, hb,
                                                   nullptr, M6, DM, DM);
    k_box<<<M6, 256, 0, stream>>>(hb, w_b2, b_b2, boxes);
  }
  k_final<<<M6, 256, 0, stream>>>(queries, w_cls, b_cls, boxes, out);
}

// Round 8
// 805.736 us; speedup vs baseline: 2.3466x; 1.0515x over previous
//
#include <hip/hip_runtime.h>
#include <hip/hip_bf16.h>
#include <math.h>

// Problem constants
#define BB 2
#define TT 4
#define CIN 128
#define DM 256
#define NQ 300
#define NP 8
#define PS 3
#define NL 6
#define HW 4096   // 64*64
#define KP 2304   // 3*3*256

typedef __attribute__((ext_vector_type(8))) short short8;
typedef __attribute__((ext_vector_type(4))) short short4_t;
typedef __attribute__((ext_vector_type(4))) float f32x4;
typedef unsigned short ushort_t;

static __device__ __forceinline__ ushort_t f2bf(float f) {
  __hip_bfloat16 h = __float2bfloat16(f);
  return *reinterpret_cast<ushort_t*>(&h);
}
static __device__ __forceinline__ float bf2f(ushort_t u) {
  return __uint_as_float(((unsigned)u) << 16);
}

// ---------------------------------------------------------------------------
// ONE mega prep kernel (block-range ladder):
//  [0,4385)       plain fp32->bf16 (w_in|w_lat|Wp2|Wo|w_b1|Wp1)
//  [4385,4641)    tct coeffs
//  [4641,6945)    wsm reorder
//  [6945,10017)   wqr merge
//  [10017,10029)  bqr merge
//  [10029,11118)  zero x2p
//  [11118,11119)  bias_comb
//  [11119,11719)  queries/boxes init
__global__ void k_prep(const float* __restrict__ w_in, const float* __restrict__ w_lat,
                       const float* __restrict__ Wp2, const float* __restrict__ Wo,
                       const float* __restrict__ w_b1, const float* __restrict__ Wp1,
                       ushort_t* __restrict__ win_bf, ushort_t* __restrict__ wlat_bf,
                       ushort_t* __restrict__ wp2_bf, ushort_t* __restrict__ wo_bf,
                       ushort_t* __restrict__ wb1_bf, ushort_t* __restrict__ wp1_bf,
                       const float* __restrict__ w_tf, ushort_t* __restrict__ tct,
                       const float* __restrict__ w_sm, ushort_t* __restrict__ wsm_bf,
                       const float* __restrict__ w_r1, const float* __restrict__ Wq,
                       ushort_t* __restrict__ wqr_bf,
                       const float* __restrict__ b_r1, const float* __restrict__ bq,
                       float* __restrict__ bqr,
                       uint4* __restrict__ x2p_zero,
                       const float* __restrict__ b_tf, const float* __restrict__ b_in,
                       float* __restrict__ bias_comb,
                       const float* __restrict__ qe, const float* __restrict__ qp,
                       const float* __restrict__ pb, float* __restrict__ queries,
                       ushort_t* __restrict__ qbf, float* __restrict__ boxes) {
  __shared__ float bt[128];
  int b = blockIdx.x, t = threadIdx.x;
  if (b < 4385) {
    int i = b * 256 + t;
    const float* s; ushort_t* d; int base;
    if (i < 8192)         { s = w_in;  d = win_bf;  base = 0; }
    else if (i < 24576)   { s = w_lat; d = wlat_bf; base = 8192; }
    else if (i < 122880)  { s = Wp2;   d = wp2_bf;  base = 24576; }
    else if (i < 221184)  { s = Wo;    d = wo_bf;   base = 122880; }
    else if (i < 237568)  { s = w_b1;  d = wb1_bf;  base = 221184; }
    else if (i < 1122304) { s = Wp1;   d = wp1_bf;  base = 237568; }
    else return;
    int j = i - base;
    float4 v = ((const float4*)s)[j];
    d[j * 4 + 0] = f2bf(v.x);
    d[j * 4 + 1] = f2bf(v.y);
    d[j * 4 + 2] = f2bf(v.z);
    d[j * 4 + 3] = f2bf(v.w);
  } else if (b < 4641) {
    int i = (b - 4385) * 256 + t;
    int k = i >> 7, c = i & 127;
    int u = k >> 7, ci = k & 127;
    const float* wp = w_tf + ((size_t)(c * 128 + ci)) * 3;
    float w0 = wp[0], w1 = wp[1], w2 = wp[2];
    float coef = (u == 0) ? (w0 + w1) : (u == 3) ? (w1 + w2) : (w0 + w1 + w2);
    tct[(size_t)k * 128 + c] = f2bf(0.25f * coef);
  } else if (b < 6945) {
    int i = (b - 4641) * 256 + t;
    int n = i / KP;
    int r = i - n * KP;
    int tp = r >> 8, c = r & 255;
    wsm_bf[i] = f2bf(w_sm[((size_t)(n * 256 + c)) * 9 + tp]);
  } else if (b < 10017) {
    int i = (b - 6945) * 256 + t;
    int l = i / (512 * 256);
    int r = i - l * 512 * 256;
    int n = r >> 8, c = r & 255;
    float v = (n < 256) ? w_r1[n * 256 + c] : Wq[((size_t)l * 256 + (n - 256)) * 256 + c];
    wqr_bf[i] = f2bf(v);
  } else if (b < 10029) {
    int i = (b - 10017) * 256 + t;
    if (i >= NL * 512) return;
    int l = i >> 9, n = i & 511;
    bqr[i] = (n < 256) ? b_r1[n] : bq[l * 256 + n - 256];
  } else if (b < 11118) {
    int j = (b - 10029) * 256 + t;
    if (j < 278784) x2p_zero[j] = make_uint4(0u, 0u, 0u, 0u);
  } else if (b < 11119) {
    int d = t;
    if (d < 128) bt[d] = b_tf[d];
    __syncthreads();
    float a = b_in[d];
    for (int c = 0; c < 128; ++c) a += w_in[d * 128 + c] * bt[c];
    bias_comb[d] = a;
  } else {
    int i = (b - 11119) * 256 + t;
    if (i < BB * NQ * DM) {
      int rd = i % (NQ * DM);
      float v = qe[rd] + qp[rd];
      queries[i] = v;
      qbf[i] = f2bf(v);
    }
    if (i < BB * NQ * 4) boxes[i] = pb[i];
  }
}

// ---------------------------------------------------------------------------
// Transpose+convert: feat (b,u,ci,s) fp32 -> featT (b*HW+s, u*128+ci) bf16.
// 64s x 64k LDS tile. grid (128, 8).
__global__ __launch_bounds__(256) void k_tr(const float* __restrict__ feat,
                                            ushort_t* __restrict__ featT) {
  __shared__ float ldsF[64][65];
  int tid = threadIdx.x;
  int gs = blockIdx.x;
  int b = gs >> 6;
  int s0 = (gs & 63) * 64;
  int k0 = blockIdx.y * 64;
  int kk = tid >> 2, sc0 = (tid & 3) * 16;
  {
    int k = k0 + kk;
    int u = k >> 7, ci = k & 127;
    const float* src = feat + (((size_t)(b * 4 + u) * 128 + ci) << 12) + s0 + sc0;
#pragma unroll
    for (int j = 0; j < 4; ++j) {
      float4 v = *(const float4*)(src + j * 4);
      ldsF[kk][sc0 + j * 4 + 0] = v.x;
      ldsF[kk][sc0 + j * 4 + 1] = v.y;
      ldsF[kk][sc0 + j * 4 + 2] = v.z;
      ldsF[kk][sc0 + j * 4 + 3] = v.w;
    }
  }
  __syncthreads();
#pragma unroll
  for (int p = 0; p < 2; ++p) {
    int idx = p * 256 + tid;
    int s_l = idx >> 3, kc = (idx & 7) * 8;
    short8 v;
#pragma unroll
    for (int j = 0; j < 8; ++j) v[j] = (short)f2bf(ldsF[kc + j][s_l]);
    *(short8*)(featT + (size_t)(b * 4096 + s0 + s_l) * 512 + k0 + kc) = v;
  }
}

// ---------------------------------------------------------------------------
// Backbone GEMM: xcl = bf16(featT . Wcomb^T + biasc + pos). BM=32, BN=64,
// grid (256,4) = 1024 blocks, register-prefetched.
__global__ __launch_bounds__(256) void k_feat2(const ushort_t* __restrict__ featT,
                                               const ushort_t* __restrict__ wcomb,
                                               const float* __restrict__ biasc,
                                               ushort_t* __restrict__ xcl) {
  __shared__ ushort_t As[32 * 36];
  __shared__ ushort_t Bs[64 * 36];
  __shared__ float dimt_s[256];
  int tid = threadIdx.x;
  {
    int dd = tid & 127;
    int ii = dd >> 1;
    dimt_s[tid] = powf(10000.0f, (2.0f * (float)(ii >> 1)) / 64.0f);
  }
  int bm = blockIdx.x * 32, bn = blockIdx.y * 64;
  int w = tid >> 6, lane = tid & 63;
  int wm = (w & 1) * 16, wn = (w >> 1) * 32;
  int q = lane >> 4, ml = lane & 15;
  int sra = tid >> 3, sca = (tid & 7) * 4;
  int srb = tid >> 2, scb = (tid & 3) * 8;
  const ushort_t* Ag = featT + (size_t)(bm + sra) * 512 + sca;
  const ushort_t* Wg = wcomb + (size_t)(bn + srb) * 512 + scb;
  f32x4 acc[2] = {};
  short4_t av = *(const short4_t*)Ag;
  short8 wv = *(const short8*)Wg;
  for (int k0 = 0; k0 < 512; k0 += 32) {
    *(short4_t*)(As + sra * 36 + sca) = av;
    *(short8*)(Bs + srb * 36 + scb) = wv;
    __syncthreads();
    if (k0 + 32 < 512) {
      av = *(const short4_t*)(Ag + k0 + 32);
      wv = *(const short8*)(Wg + k0 + 32);
    }
    short8 a = *(const short8*)(As + (wm + ml) * 36 + q * 8);
    short8 b0 = *(const short8*)(Bs + (wn + ml) * 36 + q * 8);
    short8 b1 = *(const short8*)(Bs + (wn + 16 + ml) * 36 + q * 8);
    acc[0] = __builtin_amdgcn_mfma_f32_16x16x32_bf16(a, b0, acc[0], 0, 0, 0);
    acc[1] = __builtin_amdgcn_mfma_f32_16x16x32_bf16(a, b1, acc[1], 0, 0, 0);
    __syncthreads();
  }
  const float FKT = 6.28318530717958647692f / 64.000001f;
#pragma unroll
  for (int j = 0; j < 2; ++j) {
    int cn = bn + wn + j * 16 + ml;
    float dimt = dimt_s[cn];
    float bC = biasc[cn];
    bool isx = cn >= 128;
    bool isc = cn & 1;
#pragma unroll
    for (int r = 0; r < 4; ++r) {
      int rm = bm + wm + q * 4 + r;
      int s = rm & 4095;
      int y = s >> 6, x = s & 63;
      float ang = (float)((isx ? x : y) + 1) * FKT / dimt;
      float pos = isc ? cosf(ang) : sinf(ang);
      xcl[(size_t)rm * 256 + cn] = f2bf(acc[j][r] + bC + pos);
    }
  }
}

// ---------------------------------------------------------------------------
// bf16 MFMA GEMM, BM=BN=64, BK=32.
// OUTMODE: 0 fp32 C (bias+ACT); 1 bf16 padded (B,66,66,256);
//          2 fp32 C + bf16 mirror + residual; 4 split relu|fp32 (N=512);
//          6 plain bf16; 7 merged w_b1|wqr (N=768): n<256 relu->Cf(hb),
//            256..511 relu->h1, 512..767 plain->qbuf (h1/qbuf via (float*)Cb).
template <int ACT, int OUTMODE, int MG>
__global__ __launch_bounds__(256) void k_gemm_bf16(const ushort_t* __restrict__ A,
                                                   const ushort_t* __restrict__ W,
                                                   const float* __restrict__ bias,
                                                   const float* __restrict__ res,
                                                   float* __restrict__ Cf,
                                                   ushort_t* __restrict__ Cb,
                                                   int M, int N, int K,
                                                   const ushort_t* __restrict__ W2,
                                                   const float* __restrict__ bias2) {
  __shared__ ushort_t As[64 * 36];
  __shared__ ushort_t Bs[64 * 36];
  int tid = threadIdx.x;
  int bm = blockIdx.x * 64, bn = blockIdx.y * 64;
  int w = tid >> 6, lane = tid & 63;
  int wm = (w & 1) * 32, wn = (w >> 1) * 32;
  int q = lane >> 4, ml = lane & 15;
  f32x4 acc[2][2] = {};
  int srow = tid >> 2, scol = (tid & 3) * 8;
  int ga = bm + srow;
  if (MG) ga = min(ga, M - 1);
  const ushort_t* Ag = A + (size_t)ga * K + scol;
  const ushort_t* Wg;
  if (OUTMODE == 7 && bn >= 256) Wg = W2 + (size_t)(bn - 256 + srow) * K + scol;
  else Wg = W + (size_t)(bn + srow) * K + scol;
  for (int k0 = 0; k0 < K; k0 += 32) {
    short8 av = *(const short8*)(Ag + k0);
    short8 wv = *(const short8*)(Wg + k0);
    *(short8*)(As + srow * 36 + scol) = av;
    *(short8*)(Bs + srow * 36 + scol) = wv;
    __syncthreads();
    short8 a0 = *(const short8*)(As + (wm + ml) * 36 + q * 8);
    short8 a1 = *(const short8*)(As + (wm + 16 + ml) * 36 + q * 8);
    short8 b0 = *(const short8*)(Bs + (wn + ml) * 36 + q * 8);
    short8 b1 = *(const short8*)(Bs + (wn + 16 + ml) * 36 + q * 8);
    acc[0][0] = __builtin_amdgcn_mfma_f32_16x16x32_bf16(a0, b0, acc[0][0], 0, 0, 0);
    acc[0][1] = __builtin_amdgcn_mfma_f32_16x16x32_bf16(a0, b1, acc[0][1], 0, 0, 0);
    acc[1][0] = __builtin_amdgcn_mfma_f32_16x16x32_bf16(a1, b0, acc[1][0], 0, 0, 0);
    acc[1][1] = __builtin_amdgcn_mfma_f32_16x16x32_bf16(a1, b1, acc[1][1], 0, 0, 0);
    __syncthreads();
  }
#pragma unroll
  for (int i = 0; i < 2; ++i) {
#pragma unroll
    for (int j = 0; j < 2; ++j) {
      int cn = bn + wn + j * 16 + ml;
      float bsv;
      if (OUTMODE == 7) bsv = (cn < 256) ? bias[cn] : bias2[cn - 256];
      else bsv = bias ? bias[cn] : 0.f;
#pragma unroll
      for (int r = 0; r < 4; ++r) {
        int rm = bm + wm + i * 16 + q * 4 + r;
        if (MG && rm >= M) continue;
        float v = acc[i][j][r] + bsv;
        if (OUTMODE == 0) {
          if (ACT == 1) v = fmaxf(v, 0.f);
          Cf[(size_t)rm * N + cn] = v;
        } else if (OUTMODE == 1) {
          int b = rm >> 12, rem = rm & 4095;
          int y = rem >> 6, xx = rem & 63;
          Cb[(((size_t)(b * 66 + y + 1)) * 66 + xx + 1) * 256 + cn] = f2bf(v);
        } else if (OUTMODE == 2) {
          v += res[(size_t)rm * N + cn];
          Cf[(size_t)rm * N + cn] = v;
          Cb[(size_t)rm * N + cn] = f2bf(v);
        } else if (OUTMODE == 4) {
          if (cn < 256) Cf[(size_t)rm * 256 + cn] = fmaxf(v, 0.f);
          else ((float*)Cb)[(size_t)rm * 256 + cn - 256] = v;
        } else if (OUTMODE == 6) {
          Cb[(size_t)rm * N + cn] = f2bf(v);
        } else if (OUTMODE == 7) {
          if (cn < 256) Cf[(size_t)rm * 256 + cn] = fmaxf(v, 0.f);
          else {
            float* h1qb = (float*)Cb;
            float ov = (cn < 512) ? fmaxf(v, 0.f) : v;
            h1qb[(size_t)rm * 256 + (cn & 255) + (cn >= 512 ? 153600 : 0)] = ov;
          }
        }
      }
    }
  }
}

// ---------------------------------------------------------------------------
// Wp1 split-K phase 1: grid (75,4,3), 64x64 tile, prefetched 24-iter K-loop.
__global__ __launch_bounds__(256) void k_wp1_split(const ushort_t* __restrict__ A,
                                                   const ushort_t* __restrict__ W,
                                                   float* __restrict__ part) {
  __shared__ ushort_t As[64 * 36];
  __shared__ ushort_t Bs[64 * 36];
  int tid = threadIdx.x;
  int bm = blockIdx.x * 64, bn = blockIdx.y * 64;
  int kz = blockIdx.z * 768;
  int w = tid >> 6, lane = tid & 63;
  int wm = (w & 1) * 32, wn = (w >> 1) * 32;
  int q = lane >> 4, ml = lane & 15;
  int srow = tid >> 2, scol = (tid & 3) * 8;
  const ushort_t* Ag = A + (size_t)(bm + srow) * KP + kz + scol;
  const ushort_t* Wg = W + (size_t)(bn + srow) * KP + kz + scol;
  f32x4 acc[2][2] = {};
  short8 av = *(const short8*)(Ag);
  short8 wv = *(const short8*)(Wg);
  for (int k0 = 0; k0 < 768; k0 += 32) {
    *(short8*)(As + srow * 36 + scol) = av;
    *(short8*)(Bs + srow * 36 + scol) = wv;
    __syncthreads();
    if (k0 + 32 < 768) {
      av = *(const short8*)(Ag + k0 + 32);
      wv = *(const short8*)(Wg + k0 + 32);
    }
    short8 a0 = *(const short8*)(As + (wm + ml) * 36 + q * 8);
    short8 a1 = *(const short8*)(As + (wm + 16 + ml) * 36 + q * 8);
    short8 b0 = *(const short8*)(Bs + (wn + ml) * 36 + q * 8);
    short8 b1 = *(const short8*)(Bs + (wn + 16 + ml) * 36 + q * 8);
    acc[0][0] = __builtin_amdgcn_mfma_f32_16x16x32_bf16(a0, b0, acc[0][0], 0, 0, 0);
    acc[0][1] = __builtin_amdgcn_mfma_f32_16x16x32_bf16(a0, b1, acc[0][1], 0, 0, 0);
    acc[1][0] = __builtin_amdgcn_mfma_f32_16x16x32_bf16(a1, b0, acc[1][0], 0, 0, 0);
    acc[1][1] = __builtin_amdgcn_mfma_f32_16x16x32_bf16(a1, b1, acc[1][1], 0, 0, 0);
    __syncthreads();
  }
  float* pz = part + (size_t)blockIdx.z * 4800 * 256;
#pragma unroll
  for (int i = 0; i < 2; ++i)
#pragma unroll
    for (int j = 0; j < 2; ++j) {
      int cn = bn + wn + j * 16 + ml;
#pragma unroll
      for (int r = 0; r < 4; ++r) {
        int rm = bm + wm + i * 16 + q * 4 + r;
        pz[(size_t)rm * 256 + cn] = acc[i][j][r];
      }
    }
}

// Wp1 split-K phase 2: pvm = bf16( mean_p relu( sum_z part + bias ) )
__global__ __launch_bounds__(256) void k_wp1_reduce(const float* __restrict__ part,
                                                    const float* __restrict__ bias,
                                                    ushort_t* __restrict__ pvm) {
  int row = blockIdx.x;   // 600
  int d = threadIdx.x;
  float b = bias[d];
  float s = 0.f;
#pragma unroll
  for (int p = 0; p < 8; ++p) {
    size_t idx = (size_t)(row * 8 + p) * 256 + d;
    float v = part[idx] + part[idx + (size_t)4800 * 256] +
              part[idx + (size_t)2 * 4800 * 256] + b;
    s += fmaxf(v, 0.f);
  }
  pvm[(size_t)row * 256 + d] = f2bf(s * 0.125f);
}

// ---------------------------------------------------------------------------
// 3x3 conv as GEMM, BM=32, BN=64, grid (256,4)=1024 blocks, prefetched.
__global__ __launch_bounds__(256) void k_conv3(const ushort_t* __restrict__ x2p,
                                               const ushort_t* __restrict__ wsm,
                                               const float* __restrict__ bsm,
                                               ushort_t* __restrict__ fcl) {
  __shared__ ushort_t As[32 * 36];
  __shared__ ushort_t Bs[64 * 36];
  int tid = threadIdx.x;
  int bm = blockIdx.x * 32, bn = blockIdx.y * 64;
  int w = tid >> 6, lane = tid & 63;
  int wm = (w & 1) * 16, wn = (w >> 1) * 32;
  int q = lane >> 4, ml = lane & 15;
  int sra = tid >> 3, sca = (tid & 7) * 4;
  int srb = tid >> 2, scb = (tid & 3) * 8;
  int sA = bm + sra;
  int b = sA >> 12, rem = sA & 4095;
  size_t pbase = ((size_t)(b * 66 + (rem >> 6)) * 66 + (rem & 63)) * 256;
  const ushort_t* Wg = wsm + (size_t)(bn + srb) * KP + scb;
  auto loadA = [&](int k0) {
    int ka = k0 + sca;
    int t9 = ka >> 8;
    int ky = t9 / 3, kx = t9 - ky * 3;
    return *(const short4_t*)(x2p + pbase + (size_t)(ky * 66 + kx) * 256 + (ka & 255));
  };
  f32x4 acc[2] = {};
  short4_t av = loadA(0);
  short8 wv = *(const short8*)(Wg);
  for (int k0 = 0; k0 < KP; k0 += 32) {
    *(short4_t*)(As + sra * 36 + sca) = av;
    *(short8*)(Bs + srb * 36 + scb) = wv;
    __syncthreads();
    if (k0 + 32 < KP) {
      av = loadA(k0 + 32);
      wv = *(const short8*)(Wg + k0 + 32);
    }
    short8 a = *(const short8*)(As + (wm + ml) * 36 + q * 8);
    short8 b0 = *(const short8*)(Bs + (wn + ml) * 36 + q * 8);
    short8 b1 = *(const short8*)(Bs + (wn + 16 + ml) * 36 + q * 8);
    acc[0] = __builtin_amdgcn_mfma_f32_16x16x32_bf16(a, b0, acc[0], 0, 0, 0);
    acc[1] = __builtin_amdgcn_mfma_f32_16x16x32_bf16(a, b1, acc[1], 0, 0, 0);
    __syncthreads();
  }
#pragma unroll
  for (int j = 0; j < 2; ++j) {
    int cn = bn + wn + j * 16 + ml;
    float bsv = bsm[cn];
#pragma unroll
    for (int r = 0; r < 4; ++r) {
      int rm = bm + wm + q * 4 + r;
      fcl[(size_t)rm * 256 + cn] = f2bf(acc[j][r] + bsv);
    }
  }
}

// ---------------------------------------------------------------------------
// Fused r2ref + bilinear patch sampling. Block per (b,q,p); thread = channel.
__global__ __launch_bounds__(256) void k_sample(const ushort_t* __restrict__ fcl,
                                                const float* __restrict__ h1,
                                                const float* __restrict__ w_r2,
                                                const float* __restrict__ b_r2,
                                                const float* __restrict__ boxes,
                                                ushort_t* __restrict__ flat) {
  __shared__ float pr[8];
  __shared__ float bc2[2];
  int blk = blockIdx.x;
  int row = blk >> 3, p = blk & 7;
  int b = row / NQ;
  int tid = threadIdx.x;
  float h = h1[(size_t)row * 256 + tid];
  float px = h * w_r2[(size_t)(2 * p) * 256 + tid];
  float py = h * w_r2[(size_t)(2 * p + 1) * 256 + tid];
#pragma unroll
  for (int s = 32; s > 0; s >>= 1) {
    px += __shfl_down(px, s, 64);
    py += __shfl_down(py, s, 64);
  }
  int w = tid >> 6, lane = tid & 63;
  if (lane == 0) { pr[w * 2] = px; pr[w * 2 + 1] = py; }
  __syncthreads();
  if (tid == 0) {
    float sx = pr[0] + pr[2] + pr[4] + pr[6] + b_r2[2 * p];
    float sy = pr[1] + pr[3] + pr[5] + pr[7] + b_r2[2 * p + 1];
    float rx = boxes[row * 4 + 0] + 0.5f * tanhf(sx);
    float ry = boxes[row * 4 + 1] + 0.5f * tanhf(sy);
    bc2[0] = fminf(fmaxf(rx, 0.f), 1.f);
    bc2[1] = fminf(fmaxf(ry, 0.f), 1.f);
  }
  __syncthreads();
  float rx = bc2[0], ry = bc2[1];
  int c = tid;
  const ushort_t* fb = fcl + (size_t)b * HW * DM;
  ushort_t* op = flat + (size_t)blk * KP;
#pragma unroll
  for (int jy = 0; jy < 3; ++jy) {
    float yy = (ry + (float)(jy - 1) * (1.0f / 64.0f)) * 63.0f;
    yy = fminf(fmaxf(yy, 0.f), 63.0f);
    float y0f = floorf(yy);
    float wy = yy - y0f;
    int y0 = (int)y0f;
    int y1 = min(y0 + 1, 63);
#pragma unroll
    for (int jx = 0; jx < 3; ++jx) {
      float xx = (rx + (float)(jx - 1) * (1.0f / 64.0f)) * 63.0f;
      xx = fminf(fmaxf(xx, 0.f), 63.0f);
      float x0f = floorf(xx);
      float wx = xx - x0f;
      int x0 = (int)x0f;
      int x1 = min(x0 + 1, 63);
      float v00 = bf2f(fb[(y0 * 64 + x0) * DM + c]);
      float v01 = bf2f(fb[(y0 * 64 + x1) * DM + c]);
      float v10 = bf2f(fb[(y1 * 64 + x0) * DM + c]);
      float v11 = bf2f(fb[(y1 * 64 + x1) * DM + c]);
      float v = v00 * (1.f - wx) * (1.f - wy) + v01 * wx * (1.f - wy) +
                v10 * (1.f - wx) * wy + v11 * wx * wy;
      op[(jy * 3 + jx) * DM + c] = f2bf(v);
    }
  }
}

// ---------------------------------------------------------------------------
__global__ __launch_bounds__(256) void k_attn(const float* __restrict__ qb,
                                              const float* __restrict__ kv,
                                              ushort_t* __restrict__ ao) {
  __shared__ float sc[512];
  __shared__ float qs[256];
  __shared__ float red[256];
  int row = blockIdx.x;
  int b = row / NQ;
  int tid = threadIdx.x;
  qs[tid] = qb[(size_t)row * DM + tid];
  __syncthreads();
  const float* kvb = kv + (size_t)b * NQ * DM;
  for (int k = tid; k < 512; k += 256) {
    float v = -1e30f;
    if (k < NQ) {
      const float* kp = kvb + (size_t)k * DM;
      float a = 0.f;
      for (int d = 0; d < DM; ++d) a += qs[d] * kp[d];
      v = a * (1.0f / 16.0f);
    }
    sc[k] = v;
  }
  __syncthreads();
  red[tid] = fmaxf(sc[tid], sc[tid + 256]);
  __syncthreads();
  for (int st = 128; st > 0; st >>= 1) {
    if (tid < st) red[tid] = fmaxf(red[tid], red[tid + st]);
    __syncthreads();
  }
  float mx = red[0];
  __syncthreads();
  float e0 = (tid < NQ) ? expf(sc[tid] - mx) : 0.f;
  float e1 = (tid + 256 < NQ) ? expf(sc[tid + 256] - mx) : 0.f;
  sc[tid] = e0;
  sc[tid + 256] = e1;
  red[tid] = e0 + e1;
  __syncthreads();
  for (int st = 128; st > 0; st >>= 1) {
    if (tid < st) red[tid] += red[tid + st];
    __syncthreads();
  }
  float inv = 1.0f / red[0];
  __syncthreads();
  float acc = 0.f;
  for (int k = 0; k < NQ; ++k) acc += sc[k] * kvb[(size_t)k * DM + tid];
  ao[(size_t)row * DM + tid] = f2bf(acc * inv);
}

// ---------------------------------------------------------------------------
__global__ __launch_bounds__(256) void k_box(const float* __restrict__ hb,
                                             const float* __restrict__ w_b2,
                                             const float* __restrict__ b_b2,
                                             float* __restrict__ boxes) {
  int row = blockIdx.x;
  int tid = threadIdx.x;
  int j = tid >> 6, lane = tid & 63;
  float4 hv = *(const float4*)(hb + (size_t)row * 256 + lane * 4);
  float4 wv = *(const float4*)(w_b2 + (size_t)j * 256 + lane * 4);
  float aa = hv.x * wv.x + hv.y * wv.y + hv.z * wv.z + hv.w * wv.w;
#pragma unroll
  for (int s = 32; s > 0; s >>= 1) aa += __shfl_down(aa, s, 64);
  if (lane == 0) {
    aa += b_b2[j];
    float delta = 1.0f / (1.0f + expf(-aa));
    float v = boxes[row * 4 + j] + 0.1f * tanhf(delta - 0.5f);
    boxes[row * 4 + j] = fminf(fmaxf(v, 0.f), 1.f);
  }
}

// ---------------------------------------------------------------------------
__global__ __launch_bounds__(256) void k_final(const float* __restrict__ queries,
                                               const float* __restrict__ w_cls,
                                               const float* __restrict__ b_cls,
                                               const float* __restrict__ boxes,
                                               float* __restrict__ out) {
  int row = blockIdx.x;   // 600
  int tid = threadIdx.x;
  int w = tid >> 6, lane = tid & 63;
  if (w == 0) {
    float4 qv = *(const float4*)(queries + (size_t)row * 256 + lane * 4);
    float4 wv = *(const float4*)(w_cls + lane * 4);
    float aa = qv.x * wv.x + qv.y * wv.y + qv.z * wv.z + qv.w * wv.w;
#pragma unroll
    for (int s = 32; s > 0; s >>= 1) aa += __shfl_down(aa, s, 64);
    if (lane == 0) out[row] = aa + b_cls[0];
  } else if (w == 1 && lane < 4) {
    out[600 + row * 4 + lane] = boxes[row * 4 + lane];
  }
}

// ---------------------------------------------------------------------------
extern "C" void kernel_launch(void* const* d_in, const int* in_sizes, int n_in,
                              void* d_out, int out_size, void* d_ws, size_t ws_size,
                              hipStream_t stream) {
  const float* feat   = (const float*)d_in[0];
  const float* pb     = (const float*)d_in[1];
  const float* w_tf   = (const float*)d_in[2];
  const float* b_tf   = (const float*)d_in[3];
  const float* w_in   = (const float*)d_in[4];
  const float* b_in   = (const float*)d_in[5];
  const float* w_lat  = (const float*)d_in[6];
  const float* b_lat  = (const float*)d_in[7];
  const float* w_sm   = (const float*)d_in[8];
  const float* b_sm   = (const float*)d_in[9];
  const float* q_embed= (const float*)d_in[10];
  const float* q_pos  = (const float*)d_in[11];
  const float* Wq     = (const float*)d_in[12];
  const float* bq     = (const float*)d_in[13];
  const float* Wo     = (const float*)d_in[14];
  const float* bo     = (const float*)d_in[15];
  const float* Wp1    = (const float*)d_in[16];
  const float* bp1    = (const float*)d_in[17];
  const float* Wp2    = (const float*)d_in[18];
  const float* bp2    = (const float*)d_in[19];
  const float* w_r1   = (const float*)d_in[20];
  const float* b_r1   = (const float*)d_in[21];
  const float* w_r2   = (const float*)d_in[22];
  const float* b_r2   = (const float*)d_in[23];
  const float* w_b1   = (const float*)d_in[24];
  const float* b_b1   = (const float*)d_in[25];
  const float* w_b2   = (const float*)d_in[26];
  const float* b_b2   = (const float*)d_in[27];
  const float* w_cls  = (const float*)d_in[28];
  const float* b_cls  = (const float*)d_in[29];
  float* out = (float*)d_out;

  float* ws = (float*)d_ws;
  size_t off = 0;
  auto alloc = [&](size_t n) { float* p = ws + off; off += n; return p; };
  ushort_t* flat    = (ushort_t*)alloc(5529600);   // 4800 x 2304 bf16
  float*    part    = alloc(3686400);              // 3 x 4800 x 256 fp32
  ushort_t* featT   = (ushort_t*)alloc(2097152);   // 8192 x 512 bf16
  ushort_t* xcl     = (ushort_t*)alloc(1048576);   // 8192 x 256 bf16
  ushort_t* x2p     = (ushort_t*)alloc(1115136);   // 2 x 66 x 66 x 256 bf16
  ushort_t* fcl     = (ushort_t*)alloc(1048576);   // 8192 x 256 bf16
  ushort_t* wcomb   = (ushort_t*)alloc(65536);     // 256 x 512 bf16
  ushort_t* tct     = (ushort_t*)alloc(32768);     // 512 x 128 bf16
  ushort_t* win_bf  = (ushort_t*)alloc(16384);     // 256 x 128 bf16
  float*    biasc   = alloc(256);
  ushort_t* wlat_bf = (ushort_t*)alloc(32768);
  ushort_t* wsm_bf  = (ushort_t*)alloc(294912);
  ushort_t* wp1_bf  = (ushort_t*)alloc(1769472);   // 6 x 256 x 2304
  ushort_t* wqr_bf  = (ushort_t*)alloc(393216);    // 6 x 512 x 256
  float*    bqr     = alloc(3072);                 // 6 x 512
  ushort_t* wp2_bf  = (ushort_t*)alloc(196608);    // 6 x 256 x 256
  ushort_t* wo_bf   = (ushort_t*)alloc(196608);
  ushort_t* wb1_bf  = (ushort_t*)alloc(32768);
  float* queries = alloc(153600);
  ushort_t* qbf  = (ushort_t*)alloc(76800);
  float* h1      = alloc(153600);
  float* qbuf    = alloc(153600);   // must stay contiguous after h1 (OUTMODE 7)
  float* kv      = alloc(153600);
  ushort_t* ao   = (ushort_t*)alloc(76800);
  float* hb      = alloc(153600);
  ushort_t* pvm  = (ushort_t*)alloc(76800);
  float* boxes   = alloc(2400);
  (void)ws_size; (void)in_sizes; (void)n_in; (void)out_size;

  // --- prep: everything independent in ONE launch ---
  k_prep<<<11719, 256, 0, stream>>>(w_in, w_lat, Wp2, Wo, w_b1, Wp1,
                                    win_bf, wlat_bf, wp2_bf, wo_bf, wb1_bf, wp1_bf,
                                    w_tf, tct, w_sm, wsm_bf, w_r1, Wq, wqr_bf,
                                    b_r1, bq, bqr,
                                    (uint4*)x2p, b_tf, b_in, biasc,
                                    q_embed, q_pos, pb, queries, qbf, boxes);
  k_gemm_bf16<0, 6, 0><<<dim3(4, 8), 256, 0, stream>>>(win_bf, tct, nullptr, nullptr,
                                                       nullptr, wcomb, 256, 512, 128,
                                                       nullptr, nullptr);
  // --- backbone ---
  k_tr<<<dim3(128, 8), 256, 0, stream>>>(feat, featT);
  k_feat2<<<dim3(256, 4), 256, 0, stream>>>(featT, wcomb, biasc, xcl);
  k_gemm_bf16<0, 1, 0><<<dim3(128, 4), 256, 0, stream>>>(xcl, wlat_bf, b_lat, nullptr,
                                                         nullptr, x2p, BB * HW, 256, 256,
                                                         nullptr, nullptr);
  k_conv3<<<dim3(256, 4), 256, 0, stream>>>(x2p, wsm_bf, b_sm, fcl);

  const int M6 = BB * NQ;                 // 600
  const int Mp = BB * NQ * NP;            // 4800
  dim3 g600((M6 + 63) / 64, 4);           // (10,4)
  dim3 g600w((M6 + 63) / 64, 8);          // (10,8)
  dim3 g600m((M6 + 63) / 64, 12);         // (10,12) merged N=768
  dim3 gsk(Mp / 64, 4, 3);                // (75,4,3) split-K

  // layer-0 h1|qbuf
  k_gemm_bf16<0, 4, 1><<<g600w, 256, 0, stream>>>(qbf, wqr_bf, bqr, nullptr, h1,
                                                  (ushort_t*)qbuf, M6, 512, 256,
                                                  nullptr, nullptr);
  for (int l = 0; l < NL; ++l) {
    // fused ref-point + sampling -> flat
    k_sample<<<Mp, 256, 0, stream>>>(fcl, h1, w_r2, b_r2, boxes, flat);
    // Wp1: split-K x3 + reduce(relu+pmean) -> pvm
    k_wp1_split<<<gsk, 256, 0, stream>>>(flat, wp1_bf + (size_t)l * 256 * KP, part);
    k_wp1_reduce<<<600, 256, 0, stream>>>(part, bp1 + (size_t)l * DM, pvm);
    // kv = pvm @ Wp2 + bp2
    k_gemm_bf16<0, 0, 1><<<g600, 256, 0, stream>>>(pvm, wp2_bf + (size_t)l * DM * DM,
                                                   bp2 + (size_t)l * DM, nullptr, kv,
                                                   nullptr, M6, DM, DM, nullptr, nullptr);
    k_attn<<<M6, 256, 0, stream>>>(qbuf, kv, ao);
    // queries += ao @ Wo + bo   (fp32 master + bf16 mirror)
    k_gemm_bf16<0, 2, 1><<<g600, 256, 0, stream>>>(ao, wo_bf + (size_t)l * DM * DM,
                                                   bo + (size_t)l * DM, queries, queries,
                                                   qbf, M6, DM, DM, nullptr, nullptr);
    // merged: hb = relu(q@w_b1+b_b1)  |  next-layer h1|qbuf = q@wqr[l+1]
    int ln = (l + 1) % NL;
    k_gemm_bf16<0, 7, 1><<<g600m, 256, 0, stream>>>(qbf, wb1_bf, b_b1, nullptr, hb,
                                                    (ushort_t*)h1, M6, 768, 256,
                                                    wqr_bf + (size_t)ln * 512 * 256,
                                                    bqr + ln * 512);
    k_box<<<M6, 256, 0, stream>>>(hb, w_b2, b_b2, boxes);
  }
  k_final<<<M6, 256, 0, stream>>>(queries, w_cls, b_cls, boxes, out);
}

// Round 9
// 775.239 us; speedup vs baseline: 2.4389x; 1.0393x over previous
//
#include <hip/hip_runtime.h>
#include <hip/hip_bf16.h>
#include <math.h>

// Problem constants
#define BB 2
#define TT 4
#define CIN 128
#define DM 256
#define NQ 300
#define NP 8
#define PS 3
#define NL 6
#define HW 4096   // 64*64
#define KP 2304   // 3*3*256

typedef __attribute__((ext_vector_type(8))) short short8;
typedef __attribute__((ext_vector_type(4))) short short4_t;
typedef __attribute__((ext_vector_type(4))) float f32x4;
typedef unsigned short ushort_t;

static __device__ __forceinline__ ushort_t f2bf(float f) {
  __hip_bfloat16 h = __float2bfloat16(f);
  return *reinterpret_cast<ushort_t*>(&h);
}
static __device__ __forceinline__ float bf2f(ushort_t u) {
  return __uint_as_float(((unsigned)u) << 16);
}

// ---------------------------------------------------------------------------
// ONE mega prep kernel (block-range ladder) — see round 7 notes.
__global__ void k_prep(const float* __restrict__ w_in, const float* __restrict__ w_lat,
                       const float* __restrict__ Wp2, const float* __restrict__ Wo,
                       const float* __restrict__ w_b1, const float* __restrict__ Wp1,
                       ushort_t* __restrict__ win_bf, ushort_t* __restrict__ wlat_bf,
                       ushort_t* __restrict__ wp2_bf, ushort_t* __restrict__ wo_bf,
                       ushort_t* __restrict__ wb1_bf, ushort_t* __restrict__ wp1_bf,
                       const float* __restrict__ w_tf, ushort_t* __restrict__ tct,
                       const float* __restrict__ w_sm, ushort_t* __restrict__ wsm_bf,
                       const float* __restrict__ w_r1, const float* __restrict__ Wq,
                       ushort_t* __restrict__ wqr_bf,
                       const float* __restrict__ b_r1, const float* __restrict__ bq,
                       float* __restrict__ bqr,
                       uint4* __restrict__ x2p_zero,
                       const float* __restrict__ b_tf, const float* __restrict__ b_in,
                       float* __restrict__ bias_comb,
                       const float* __restrict__ qe, const float* __restrict__ qp,
                       const float* __restrict__ pb, float* __restrict__ queries,
                       ushort_t* __restrict__ qbf, float* __restrict__ boxes) {
  __shared__ float bt[128];
  int b = blockIdx.x, t = threadIdx.x;
  if (b < 4385) {
    int i = b * 256 + t;
    const float* s; ushort_t* d; int base;
    if (i < 8192)         { s = w_in;  d = win_bf;  base = 0; }
    else if (i < 24576)   { s = w_lat; d = wlat_bf; base = 8192; }
    else if (i < 122880)  { s = Wp2;   d = wp2_bf;  base = 24576; }
    else if (i < 221184)  { s = Wo;    d = wo_bf;   base = 122880; }
    else if (i < 237568)  { s = w_b1;  d = wb1_bf;  base = 221184; }
    else if (i < 1122304) { s = Wp1;   d = wp1_bf;  base = 237568; }
    else return;
    int j = i - base;
    float4 v = ((const float4*)s)[j];
    d[j * 4 + 0] = f2bf(v.x);
    d[j * 4 + 1] = f2bf(v.y);
    d[j * 4 + 2] = f2bf(v.z);
    d[j * 4 + 3] = f2bf(v.w);
  } else if (b < 4641) {
    int i = (b - 4385) * 256 + t;
    int k = i >> 7, c = i & 127;
    int u = k >> 7, ci = k & 127;
    const float* wp = w_tf + ((size_t)(c * 128 + ci)) * 3;
    float w0 = wp[0], w1 = wp[1], w2 = wp[2];
    float coef = (u == 0) ? (w0 + w1) : (u == 3) ? (w1 + w2) : (w0 + w1 + w2);
    tct[(size_t)k * 128 + c] = f2bf(0.25f * coef);
  } else if (b < 6945) {
    int i = (b - 4641) * 256 + t;
    int n = i / KP;
    int r = i - n * KP;
    int tp = r >> 8, c = r & 255;
    wsm_bf[i] = f2bf(w_sm[((size_t)(n * 256 + c)) * 9 + tp]);
  } else if (b < 10017) {
    int i = (b - 6945) * 256 + t;
    int l = i / (512 * 256);
    int r = i - l * 512 * 256;
    int n = r >> 8, c = r & 255;
    float v = (n < 256) ? w_r1[n * 256 + c] : Wq[((size_t)l * 256 + (n - 256)) * 256 + c];
    wqr_bf[i] = f2bf(v);
  } else if (b < 10029) {
    int i = (b - 10017) * 256 + t;
    if (i >= NL * 512) return;
    int l = i >> 9, n = i & 511;
    bqr[i] = (n < 256) ? b_r1[n] : bq[l * 256 + n - 256];
  } else if (b < 11118) {
    int j = (b - 10029) * 256 + t;
    if (j < 278784) x2p_zero[j] = make_uint4(0u, 0u, 0u, 0u);
  } else if (b < 11119) {
    int d = t;
    if (d < 128) bt[d] = b_tf[d];
    __syncthreads();
    float a = b_in[d];
    for (int c = 0; c < 128; ++c) a += w_in[d * 128 + c] * bt[c];
    bias_comb[d] = a;
  } else {
    int i = (b - 11119) * 256 + t;
    if (i < BB * NQ * DM) {
      int rd = i % (NQ * DM);
      float v = qe[rd] + qp[rd];
      queries[i] = v;
      qbf[i] = f2bf(v);
    }
    if (i < BB * NQ * 4) boxes[i] = pb[i];
  }
}

// ---------------------------------------------------------------------------
// Transpose+convert: feat (b,u,ci,s) fp32 -> featT (b*HW+s, u*128+ci) bf16.
__global__ __launch_bounds__(256) void k_tr(const float* __restrict__ feat,
                                            ushort_t* __restrict__ featT) {
  __shared__ float ldsF[64][65];
  int tid = threadIdx.x;
  int gs = blockIdx.x;
  int b = gs >> 6;
  int s0 = (gs & 63) * 64;
  int k0 = blockIdx.y * 64;
  int kk = tid >> 2, sc0 = (tid & 3) * 16;
  {
    int k = k0 + kk;
    int u = k >> 7, ci = k & 127;
    const float* src = feat + (((size_t)(b * 4 + u) * 128 + ci) << 12) + s0 + sc0;
#pragma unroll
    for (int j = 0; j < 4; ++j) {
      float4 v = *(const float4*)(src + j * 4);
      ldsF[kk][sc0 + j * 4 + 0] = v.x;
      ldsF[kk][sc0 + j * 4 + 1] = v.y;
      ldsF[kk][sc0 + j * 4 + 2] = v.z;
      ldsF[kk][sc0 + j * 4 + 3] = v.w;
    }
  }
  __syncthreads();
#pragma unroll
  for (int p = 0; p < 2; ++p) {
    int idx = p * 256 + tid;
    int s_l = idx >> 3, kc = (idx & 7) * 8;
    short8 v;
#pragma unroll
    for (int j = 0; j < 8; ++j) v[j] = (short)f2bf(ldsF[kc + j][s_l]);
    *(short8*)(featT + (size_t)(b * 4096 + s0 + s_l) * 512 + k0 + kc) = v;
  }
}

// ---------------------------------------------------------------------------
// Backbone GEMM: xcl = bf16(featT . Wcomb^T + biasc + pos). BM=32, BN=64.
__global__ __launch_bounds__(256) void k_feat2(const ushort_t* __restrict__ featT,
                                               const ushort_t* __restrict__ wcomb,
                                               const float* __restrict__ biasc,
                                               ushort_t* __restrict__ xcl) {
  __shared__ ushort_t As[32 * 36];
  __shared__ ushort_t Bs[64 * 36];
  __shared__ float dimt_s[256];
  int tid = threadIdx.x;
  {
    int dd = tid & 127;
    int ii = dd >> 1;
    dimt_s[tid] = powf(10000.0f, (2.0f * (float)(ii >> 1)) / 64.0f);
  }
  int bm = blockIdx.x * 32, bn = blockIdx.y * 64;
  int w = tid >> 6, lane = tid & 63;
  int wm = (w & 1) * 16, wn = (w >> 1) * 32;
  int q = lane >> 4, ml = lane & 15;
  int sra = tid >> 3, sca = (tid & 7) * 4;
  int srb = tid >> 2, scb = (tid & 3) * 8;
  const ushort_t* Ag = featT + (size_t)(bm + sra) * 512 + sca;
  const ushort_t* Wg = wcomb + (size_t)(bn + srb) * 512 + scb;
  f32x4 acc[2] = {};
  short4_t av = *(const short4_t*)Ag;
  short8 wv = *(const short8*)Wg;
  for (int k0 = 0; k0 < 512; k0 += 32) {
    *(short4_t*)(As + sra * 36 + sca) = av;
    *(short8*)(Bs + srb * 36 + scb) = wv;
    __syncthreads();
    if (k0 + 32 < 512) {
      av = *(const short4_t*)(Ag + k0 + 32);
      wv = *(const short8*)(Wg + k0 + 32);
    }
    short8 a = *(const short8*)(As + (wm + ml) * 36 + q * 8);
    short8 b0 = *(const short8*)(Bs + (wn + ml) * 36 + q * 8);
    short8 b1 = *(const short8*)(Bs + (wn + 16 + ml) * 36 + q * 8);
    acc[0] = __builtin_amdgcn_mfma_f32_16x16x32_bf16(a, b0, acc[0], 0, 0, 0);
    acc[1] = __builtin_amdgcn_mfma_f32_16x16x32_bf16(a, b1, acc[1], 0, 0, 0);
    __syncthreads();
  }
  const float FKT = 6.28318530717958647692f / 64.000001f;
#pragma unroll
  for (int j = 0; j < 2; ++j) {
    int cn = bn + wn + j * 16 + ml;
    float dimt = dimt_s[cn];
    float bC = biasc[cn];
    bool isx = cn >= 128;
    bool isc = cn & 1;
#pragma unroll
    for (int r = 0; r < 4; ++r) {
      int rm = bm + wm + q * 4 + r;
      int s = rm & 4095;
      int y = s >> 6, x = s & 63;
      float ang = (float)((isx ? x : y) + 1) * FKT / dimt;
      float pos = isc ? cosf(ang) : sinf(ang);
      xcl[(size_t)rm * 256 + cn] = f2bf(acc[j][r] + bC + pos);
    }
  }
}

// ---------------------------------------------------------------------------
// bf16 MFMA GEMM, BM=BN=64, BK=32.
// OUTMODE: 0 fp32 C (bias+ACT); 1 bf16 padded (B,66,66,256);
//          2 fp32 C + bf16 mirror + residual; 4 split relu->Cf | bf16->Cb (N=512);
//          6 plain bf16 out; 7 merged w_b1|wqr (N=768): n<256 relu->Cf(hb),
//            256..511 relu->(float*)Cb (h1), 512..767 bf16->(ushort*)res (qb2).
template <int ACT, int OUTMODE, int MG>
__global__ __launch_bounds__(256) void k_gemm_bf16(const ushort_t* __restrict__ A,
                                                   const ushort_t* __restrict__ W,
                                                   const float* __restrict__ bias,
                                                   const float* __restrict__ res,
                                                   float* __restrict__ Cf,
                                                   ushort_t* __restrict__ Cb,
                                                   int M, int N, int K,
                                                   const ushort_t* __restrict__ W2,
                                                   const float* __restrict__ bias2) {
  __shared__ ushort_t As[64 * 36];
  __shared__ ushort_t Bs[64 * 36];
  int tid = threadIdx.x;
  int bm = blockIdx.x * 64, bn = blockIdx.y * 64;
  int w = tid >> 6, lane = tid & 63;
  int wm = (w & 1) * 32, wn = (w >> 1) * 32;
  int q = lane >> 4, ml = lane & 15;
  f32x4 acc[2][2] = {};
  int srow = tid >> 2, scol = (tid & 3) * 8;
  int ga = bm + srow;
  if (MG) ga = min(ga, M - 1);
  const ushort_t* Ag = A + (size_t)ga * K + scol;
  const ushort_t* Wg;
  if (OUTMODE == 7 && bn >= 256) Wg = W2 + (size_t)(bn - 256 + srow) * K + scol;
  else Wg = W + (size_t)(bn + srow) * K + scol;
  for (int k0 = 0; k0 < K; k0 += 32) {
    short8 av = *(const short8*)(Ag + k0);
    short8 wv = *(const short8*)(Wg + k0);
    *(short8*)(As + srow * 36 + scol) = av;
    *(short8*)(Bs + srow * 36 + scol) = wv;
    __syncthreads();
    short8 a0 = *(const short8*)(As + (wm + ml) * 36 + q * 8);
    short8 a1 = *(const short8*)(As + (wm + 16 + ml) * 36 + q * 8);
    short8 b0 = *(const short8*)(Bs + (wn + ml) * 36 + q * 8);
    short8 b1 = *(const short8*)(Bs + (wn + 16 + ml) * 36 + q * 8);
    acc[0][0] = __builtin_amdgcn_mfma_f32_16x16x32_bf16(a0, b0, acc[0][0], 0, 0, 0);
    acc[0][1] = __builtin_amdgcn_mfma_f32_16x16x32_bf16(a0, b1, acc[0][1], 0, 0, 0);
    acc[1][0] = __builtin_amdgcn_mfma_f32_16x16x32_bf16(a1, b0, acc[1][0], 0, 0, 0);
    acc[1][1] = __builtin_amdgcn_mfma_f32_16x16x32_bf16(a1, b1, acc[1][1], 0, 0, 0);
    __syncthreads();
  }
#pragma unroll
  for (int i = 0; i < 2; ++i) {
#pragma unroll
    for (int j = 0; j < 2; ++j) {
      int cn = bn + wn + j * 16 + ml;
      float bsv;
      if (OUTMODE == 7) bsv = (cn < 256) ? bias[cn] : bias2[cn - 256];
      else bsv = bias ? bias[cn] : 0.f;
#pragma unroll
      for (int r = 0; r < 4; ++r) {
        int rm = bm + wm + i * 16 + q * 4 + r;
        if (MG && rm >= M) continue;
        float v = acc[i][j][r] + bsv;
        if (OUTMODE == 0) {
          if (ACT == 1) v = fmaxf(v, 0.f);
          Cf[(size_t)rm * N + cn] = v;
        } else if (OUTMODE == 1) {
          int b = rm >> 12, rem = rm & 4095;
          int y = rem >> 6, xx = rem & 63;
          Cb[(((size_t)(b * 66 + y + 1)) * 66 + xx + 1) * 256 + cn] = f2bf(v);
        } else if (OUTMODE == 2) {
          v += res[(size_t)rm * N + cn];
          Cf[(size_t)rm * N + cn] = v;
          Cb[(size_t)rm * N + cn] = f2bf(v);
        } else if (OUTMODE == 4) {
          if (cn < 256) Cf[(size_t)rm * 256 + cn] = fmaxf(v, 0.f);
          else Cb[(size_t)rm * 256 + cn - 256] = f2bf(v);
        } else if (OUTMODE == 6) {
          Cb[(size_t)rm * N + cn] = f2bf(v);
        } else if (OUTMODE == 7) {
          if (cn < 256) Cf[(size_t)rm * 256 + cn] = fmaxf(v, 0.f);
          else if (cn < 512) ((float*)Cb)[(size_t)rm * 256 + cn - 256] = fmaxf(v, 0.f);
          else ((ushort_t*)res)[(size_t)rm * 256 + cn - 512] = f2bf(v);
        }
      }
    }
  }
}

// ---------------------------------------------------------------------------
// Wp1 split-K phase 1: grid (75,4,3), 64x64 tile, prefetched 24-iter K-loop.
__global__ __launch_bounds__(256) void k_wp1_split(const ushort_t* __restrict__ A,
                                                   const ushort_t* __restrict__ W,
                                                   float* __restrict__ part) {
  __shared__ ushort_t As[64 * 36];
  __shared__ ushort_t Bs[64 * 36];
  int tid = threadIdx.x;
  int bm = blockIdx.x * 64, bn = blockIdx.y * 64;
  int kz = blockIdx.z * 768;
  int w = tid >> 6, lane = tid & 63;
  int wm = (w & 1) * 32, wn = (w >> 1) * 32;
  int q = lane >> 4, ml = lane & 15;
  int srow = tid >> 2, scol = (tid & 3) * 8;
  const ushort_t* Ag = A + (size_t)(bm + srow) * KP + kz + scol;
  const ushort_t* Wg = W + (size_t)(bn + srow) * KP + kz + scol;
  f32x4 acc[2][2] = {};
  short8 av = *(const short8*)(Ag);
  short8 wv = *(const short8*)(Wg);
  for (int k0 = 0; k0 < 768; k0 += 32) {
    *(short8*)(As + srow * 36 + scol) = av;
    *(short8*)(Bs + srow * 36 + scol) = wv;
    __syncthreads();
    if (k0 + 32 < 768) {
      av = *(const short8*)(Ag + k0 + 32);
      wv = *(const short8*)(Wg + k0 + 32);
    }
    short8 a0 = *(const short8*)(As + (wm + ml) * 36 + q * 8);
    short8 a1 = *(const short8*)(As + (wm + 16 + ml) * 36 + q * 8);
    short8 b0 = *(const short8*)(Bs + (wn + ml) * 36 + q * 8);
    short8 b1 = *(const short8*)(Bs + (wn + 16 + ml) * 36 + q * 8);
    acc[0][0] = __builtin_amdgcn_mfma_f32_16x16x32_bf16(a0, b0, acc[0][0], 0, 0, 0);
    acc[0][1] = __builtin_amdgcn_mfma_f32_16x16x32_bf16(a0, b1, acc[0][1], 0, 0, 0);
    acc[1][0] = __builtin_amdgcn_mfma_f32_16x16x32_bf16(a1, b0, acc[1][0], 0, 0, 0);
    acc[1][1] = __builtin_amdgcn_mfma_f32_16x16x32_bf16(a1, b1, acc[1][1], 0, 0, 0);
    __syncthreads();
  }
  float* pz = part + (size_t)blockIdx.z * 4800 * 256;
#pragma unroll
  for (int i = 0; i < 2; ++i)
#pragma unroll
    for (int j = 0; j < 2; ++j) {
      int cn = bn + wn + j * 16 + ml;
#pragma unroll
      for (int r = 0; r < 4; ++r) {
        int rm = bm + wm + i * 16 + q * 4 + r;
        pz[(size_t)rm * 256 + cn] = acc[i][j][r];
      }
    }
}

// Wp1 split-K phase 2: pvm = bf16( mean_p relu( sum_z part + bias ) )
__global__ __launch_bounds__(256) void k_wp1_reduce(const float* __restrict__ part,
                                                    const float* __restrict__ bias,
                                                    ushort_t* __restrict__ pvm) {
  int row = blockIdx.x;   // 600
  int d = threadIdx.x;
  float b = bias[d];
  float s = 0.f;
#pragma unroll
  for (int p = 0; p < 8; ++p) {
    size_t idx = (size_t)(row * 8 + p) * 256 + d;
    float v = part[idx] + part[idx + (size_t)4800 * 256] +
              part[idx + (size_t)2 * 4800 * 256] + b;
    s += fmaxf(v, 0.f);
  }
  pvm[(size_t)row * 256 + d] = f2bf(s * 0.125f);
}

// ---------------------------------------------------------------------------
// 3x3 conv as GEMM, BM=32, BN=64, grid (256,4)=1024 blocks, prefetched.
__global__ __launch_bounds__(256) void k_conv3(const ushort_t* __restrict__ x2p,
                                               const ushort_t* __restrict__ wsm,
                                               const float* __restrict__ bsm,
                                               ushort_t* __restrict__ fcl) {
  __shared__ ushort_t As[32 * 36];
  __shared__ ushort_t Bs[64 * 36];
  int tid = threadIdx.x;
  int bm = blockIdx.x * 32, bn = blockIdx.y * 64;
  int w = tid >> 6, lane = tid & 63;
  int wm = (w & 1) * 16, wn = (w >> 1) * 32;
  int q = lane >> 4, ml = lane & 15;
  int sra = tid >> 3, sca = (tid & 7) * 4;
  int srb = tid >> 2, scb = (tid & 3) * 8;
  int sA = bm + sra;
  int b = sA >> 12, rem = sA & 4095;
  size_t pbase = ((size_t)(b * 66 + (rem >> 6)) * 66 + (rem & 63)) * 256;
  const ushort_t* Wg = wsm + (size_t)(bn + srb) * KP + scb;
  auto loadA = [&](int k0) {
    int ka = k0 + sca;
    int t9 = ka >> 8;
    int ky = t9 / 3, kx = t9 - ky * 3;
    return *(const short4_t*)(x2p + pbase + (size_t)(ky * 66 + kx) * 256 + (ka & 255));
  };
  f32x4 acc[2] = {};
  short4_t av = loadA(0);
  short8 wv = *(const short8*)(Wg);
  for (int k0 = 0; k0 < KP; k0 += 32) {
    *(short4_t*)(As + sra * 36 + sca) = av;
    *(short8*)(Bs + srb * 36 + scb) = wv;
    __syncthreads();
    if (k0 + 32 < KP) {
      av = loadA(k0 + 32);
      wv = *(const short8*)(Wg + k0 + 32);
    }
    short8 a = *(const short8*)(As + (wm + ml) * 36 + q * 8);
    short8 b0 = *(const short8*)(Bs + (wn + ml) * 36 + q * 8);
    short8 b1 = *(const short8*)(Bs + (wn + 16 + ml) * 36 + q * 8);
    acc[0] = __builtin_amdgcn_mfma_f32_16x16x32_bf16(a, b0, acc[0], 0, 0, 0);
    acc[1] = __builtin_amdgcn_mfma_f32_16x16x32_bf16(a, b1, acc[1], 0, 0, 0);
    __syncthreads();
  }
#pragma unroll
  for (int j = 0; j < 2; ++j) {
    int cn = bn + wn + j * 16 + ml;
    float bsv = bsm[cn];
#pragma unroll
    for (int r = 0; r < 4; ++r) {
      int rm = bm + wm + q * 4 + r;
      fcl[(size_t)rm * 256 + cn] = f2bf(acc[j][r] + bsv);
    }
  }
}

// ---------------------------------------------------------------------------
// Fused r2ref + bilinear patch sampling. Block per (b,q,p); thread = channel.
__global__ __launch_bounds__(256) void k_sample(const ushort_t* __restrict__ fcl,
                                                const float* __restrict__ h1,
                                                const float* __restrict__ w_r2,
                                                const float* __restrict__ b_r2,
                                                const float* __restrict__ boxes,
                                                ushort_t* __restrict__ flat) {
  __shared__ float pr[8];
  __shared__ float bc2[2];
  int blk = blockIdx.x;
  int row = blk >> 3, p = blk & 7;
  int b = row / NQ;
  int tid = threadIdx.x;
  float h = h1[(size_t)row * 256 + tid];
  float px = h * w_r2[(size_t)(2 * p) * 256 + tid];
  float py = h * w_r2[(size_t)(2 * p + 1) * 256 + tid];
#pragma unroll
  for (int s = 32; s > 0; s >>= 1) {
    px += __shfl_down(px, s, 64);
    py += __shfl_down(py, s, 64);
  }
  int w = tid >> 6, lane = tid & 63;
  if (lane == 0) { pr[w * 2] = px; pr[w * 2 + 1] = py; }
  __syncthreads();
  if (tid == 0) {
    float sx = pr[0] + pr[2] + pr[4] + pr[6] + b_r2[2 * p];
    float sy = pr[1] + pr[3] + pr[5] + pr[7] + b_r2[2 * p + 1];
    float rx = boxes[row * 4 + 0] + 0.5f * tanhf(sx);
    float ry = boxes[row * 4 + 1] + 0.5f * tanhf(sy);
    bc2[0] = fminf(fmaxf(rx, 0.f), 1.f);
    bc2[1] = fminf(fmaxf(ry, 0.f), 1.f);
  }
  __syncthreads();
  float rx = bc2[0], ry = bc2[1];
  int c = tid;
  const ushort_t* fb = fcl + (size_t)b * HW * DM;
  ushort_t* op = flat + (size_t)blk * KP;
#pragma unroll
  for (int jy = 0; jy < 3; ++jy) {
    float yy = (ry + (float)(jy - 1) * (1.0f / 64.0f)) * 63.0f;
    yy = fminf(fmaxf(yy, 0.f), 63.0f);
    float y0f = floorf(yy);
    float wy = yy - y0f;
    int y0 = (int)y0f;
    int y1 = min(y0 + 1, 63);
#pragma unroll
    for (int jx = 0; jx < 3; ++jx) {
      float xx = (rx + (float)(jx - 1) * (1.0f / 64.0f)) * 63.0f;
      xx = fminf(fmaxf(xx, 0.f), 63.0f);
      float x0f = floorf(xx);
      float wx = xx - x0f;
      int x0 = (int)x0f;
      int x1 = min(x0 + 1, 63);
      float v00 = bf2f(fb[(y0 * 64 + x0) * DM + c]);
      float v01 = bf2f(fb[(y0 * 64 + x1) * DM + c]);
      float v10 = bf2f(fb[(y1 * 64 + x0) * DM + c]);
      float v11 = bf2f(fb[(y1 * 64 + x1) * DM + c]);
      float v = v00 * (1.f - wx) * (1.f - wy) + v01 * wx * (1.f - wy) +
                v10 * (1.f - wx) * wy + v11 * wx * wy;
      op[(jy * 3 + jx) * DM + c] = f2bf(v);
    }
  }
}

// ---------------------------------------------------------------------------
// Attention, all-bf16 inputs: qb2 (600x256 bf16), kvb (600x256 bf16).
// Vectorized ushort8 kv-row loads in the score phase; coalesced bf16 phase 2.
__global__ __launch_bounds__(256) void k_attn(const ushort_t* __restrict__ qb2,
                                              const ushort_t* __restrict__ kvb,
                                              ushort_t* __restrict__ ao) {
  __shared__ float qs[256];
  __shared__ float sc[512];
  __shared__ float red[256];
  int row = blockIdx.x;
  int b = row / NQ;
  int tid = threadIdx.x;
  qs[tid] = bf2f(qb2[(size_t)row * DM + tid]);
  __syncthreads();
  const ushort_t* kvB = kvb + (size_t)b * NQ * DM;
#pragma unroll
  for (int s2 = 0; s2 < 2; ++s2) {
    int k = tid + s2 * 256;
    float v = -1e30f;
    if (k < NQ) {
      const ushort_t* kp = kvB + (size_t)k * DM;
      float a = 0.f;
#pragma unroll
      for (int d = 0; d < 256; d += 8) {
        short8 k8 = *(const short8*)(kp + d);
        const float* qd = qs + d;
        a += bf2f((ushort_t)k8[0]) * qd[0];
        a += bf2f((ushort_t)k8[1]) * qd[1];
        a += bf2f((ushort_t)k8[2]) * qd[2];
        a += bf2f((ushort_t)k8[3]) * qd[3];
        a += bf2f((ushort_t)k8[4]) * qd[4];
        a += bf2f((ushort_t)k8[5]) * qd[5];
        a += bf2f((ushort_t)k8[6]) * qd[6];
        a += bf2f((ushort_t)k8[7]) * qd[7];
      }
      v = a * (1.0f / 16.0f);
    }
    sc[k] = v;
  }
  __syncthreads();
  red[tid] = fmaxf(sc[tid], sc[tid + 256]);
  __syncthreads();
  for (int st = 128; st > 0; st >>= 1) {
    if (tid < st) red[tid] = fmaxf(red[tid], red[tid + st]);
    __syncthreads();
  }
  float mx = red[0];
  __syncthreads();
  float e0 = (tid < NQ) ? expf(sc[tid] - mx) : 0.f;
  float e1 = (tid + 256 < NQ) ? expf(sc[tid + 256] - mx) : 0.f;
  sc[tid] = e0;
  sc[tid + 256] = e1;
  red[tid] = e0 + e1;
  __syncthreads();
  for (int st = 128; st > 0; st >>= 1) {
    if (tid < st) red[tid] += red[tid + st];
    __syncthreads();
  }
  float inv = 1.0f / red[0];
  __syncthreads();
  float acc = 0.f;
#pragma unroll 4
  for (int k = 0; k < NQ; ++k)
    acc += sc[k] * bf2f(kvB[(size_t)k * DM + tid]);
  ao[(size_t)row * DM + tid] = f2bf(acc * inv);
}

// ---------------------------------------------------------------------------
// box update (+ fused final-output when last != 0).
__global__ __launch_bounds__(256) void k_boxf(const float* __restrict__ hb,
                                              const float* __restrict__ w_b2,
                                              const float* __restrict__ b_b2,
                                              float* __restrict__ boxes,
                                              int last,
                                              const float* __restrict__ queries,
                                              const float* __restrict__ w_cls,
                                              const float* __restrict__ b_cls,
                                              float* __restrict__ out) {
  __shared__ float nb[4];
  int row = blockIdx.x;
  int tid = threadIdx.x;
  int j = tid >> 6, lane = tid & 63;
  float4 hv = *(const float4*)(hb + (size_t)row * 256 + lane * 4);
  float4 wv = *(const float4*)(w_b2 + (size_t)j * 256 + lane * 4);
  float aa = hv.x * wv.x + hv.y * wv.y + hv.z * wv.z + hv.w * wv.w;
#pragma unroll
  for (int s = 32; s > 0; s >>= 1) aa += __shfl_down(aa, s, 64);
  if (lane == 0) {
    aa += b_b2[j];
    float delta = 1.0f / (1.0f + expf(-aa));
    float v = boxes[row * 4 + j] + 0.1f * tanhf(delta - 0.5f);
    v = fminf(fmaxf(v, 0.f), 1.f);
    boxes[row * 4 + j] = v;
    nb[j] = v;
  }
  if (last) {
    __syncthreads();
    if (j == 0) {
      float4 qv = *(const float4*)(queries + (size_t)row * 256 + lane * 4);
      float4 cv = *(const float4*)(w_cls + lane * 4);
      float a2 = qv.x * cv.x + qv.y * cv.y + qv.z * cv.z + qv.w * cv.w;
#pragma unroll
      for (int s = 32; s > 0; s >>= 1) a2 += __shfl_down(a2, s, 64);
      if (lane == 0) out[row] = a2 + b_cls[0];
    } else if (j == 1 && lane < 4) {
      out[600 + row * 4 + lane] = nb[lane];
    }
  }
}

// ---------------------------------------------------------------------------
extern "C" void kernel_launch(void* const* d_in, const int* in_sizes, int n_in,
                              void* d_out, int out_size, void* d_ws, size_t ws_size,
                              hipStream_t stream) {
  const float* feat   = (const float*)d_in[0];
  const float* pb     = (const float*)d_in[1];
  const float* w_tf   = (const float*)d_in[2];
  const float* b_tf   = (const float*)d_in[3];
  const float* w_in   = (const float*)d_in[4];
  const float* b_in   = (const float*)d_in[5];
  const float* w_lat  = (const float*)d_in[6];
  const float* b_lat  = (const float*)d_in[7];
  const float* w_sm   = (const float*)d_in[8];
  const float* b_sm   = (const float*)d_in[9];
  const float* q_embed= (const float*)d_in[10];
  const float* q_pos  = (const float*)d_in[11];
  const float* Wq     = (const float*)d_in[12];
  const float* bq     = (const float*)d_in[13];
  const float* Wo     = (const float*)d_in[14];
  const float* bo     = (const float*)d_in[15];
  const float* Wp1    = (const float*)d_in[16];
  const float* bp1    = (const float*)d_in[17];
  const float* Wp2    = (const float*)d_in[18];
  const float* bp2    = (const float*)d_in[19];
  const float* w_r1   = (const float*)d_in[20];
  const float* b_r1   = (const float*)d_in[21];
  const float* w_r2   = (const float*)d_in[22];
  const float* b_r2   = (const float*)d_in[23];
  const float* w_b1   = (const float*)d_in[24];
  const float* b_b1   = (const float*)d_in[25];
  const float* w_b2   = (const float*)d_in[26];
  const float* b_b2   = (const float*)d_in[27];
  const float* w_cls  = (const float*)d_in[28];
  const float* b_cls  = (const float*)d_in[29];
  float* out = (float*)d_out;

  float* ws = (float*)d_ws;
  size_t off = 0;
  auto alloc = [&](size_t n) { float* p = ws + off; off += n; return p; };
  ushort_t* flat    = (ushort_t*)alloc(5529600);   // 4800 x 2304 bf16
  float*    part    = alloc(3686400);              // 3 x 4800 x 256 fp32
  ushort_t* featT   = (ushort_t*)alloc(2097152);   // 8192 x 512 bf16
  ushort_t* xcl     = (ushort_t*)alloc(1048576);   // 8192 x 256 bf16
  ushort_t* x2p     = (ushort_t*)alloc(1115136);   // 2 x 66 x 66 x 256 bf16
  ushort_t* fcl     = (ushort_t*)alloc(1048576);   // 8192 x 256 bf16
  ushort_t* wcomb   = (ushort_t*)alloc(65536);     // 256 x 512 bf16
  ushort_t* tct     = (ushort_t*)alloc(32768);     // 512 x 128 bf16
  ushort_t* win_bf  = (ushort_t*)alloc(16384);     // 256 x 128 bf16
  float*    biasc   = alloc(256);
  ushort_t* wlat_bf = (ushort_t*)alloc(32768);
  ushort_t* wsm_bf  = (ushort_t*)alloc(294912);
  ushort_t* wp1_bf  = (ushort_t*)alloc(1769472);   // 6 x 256 x 2304
  ushort_t* wqr_bf  = (ushort_t*)alloc(393216);    // 6 x 512 x 256
  float*    bqr     = alloc(3072);                 // 6 x 512
  ushort_t* wp2_bf  = (ushort_t*)alloc(196608);    // 6 x 256 x 256
  ushort_t* wo_bf   = (ushort_t*)alloc(196608);
  ushort_t* wb1_bf  = (ushort_t*)alloc(32768);
  float* queries = alloc(153600);
  ushort_t* qbf  = (ushort_t*)alloc(76800);
  float* h1      = alloc(153600);
  ushort_t* qb2  = (ushort_t*)alloc(76800);        // bf16 q for attention
  ushort_t* kvb  = (ushort_t*)alloc(76800);        // bf16 kv
  ushort_t* ao   = (ushort_t*)alloc(76800);
  float* hb      = alloc(153600);
  ushort_t* pvm  = (ushort_t*)alloc(76800);
  float* boxes   = alloc(2400);
  (void)ws_size; (void)in_sizes; (void)n_in; (void)out_size;

  // --- prep: everything independent in ONE launch ---
  k_prep<<<11719, 256, 0, stream>>>(w_in, w_lat, Wp2, Wo, w_b1, Wp1,
                                    win_bf, wlat_bf, wp2_bf, wo_bf, wb1_bf, wp1_bf,
                                    w_tf, tct, w_sm, wsm_bf, w_r1, Wq, wqr_bf,
                                    b_r1, bq, bqr,
                                    (uint4*)x2p, b_tf, b_in, biasc,
                                    q_embed, q_pos, pb, queries, qbf, boxes);
  k_gemm_bf16<0, 6, 0><<<dim3(4, 8), 256, 0, stream>>>(win_bf, tct, nullptr, nullptr,
                                                       nullptr, wcomb, 256, 512, 128,
                                                       nullptr, nullptr);
  // --- backbone ---
  k_tr<<<dim3(128, 8), 256, 0, stream>>>(feat, featT);
  k_feat2<<<dim3(256, 4), 256, 0, stream>>>(featT, wcomb, biasc, xcl);
  k_gemm_bf16<0, 1, 0><<<dim3(128, 4), 256, 0, stream>>>(xcl, wlat_bf, b_lat, nullptr,
                                                         nullptr, x2p, BB * HW, 256, 256,
                                                         nullptr, nullptr);
  k_conv3<<<dim3(256, 4), 256, 0, stream>>>(x2p, wsm_bf, b_sm, fcl);

  const int M6 = BB * NQ;                 // 600
  const int Mp = BB * NQ * NP;            // 4800
  dim3 g600((M6 + 63) / 64, 4);           // (10,4)
  dim3 g600w((M6 + 63) / 64, 8);          // (10,8)
  dim3 g600m((M6 + 63) / 64, 12);         // (10,12) merged N=768
  dim3 gsk(Mp / 64, 4, 3);                // (75,4,3) split-K

  // layer-0 h1 | qb2
  k_gemm_bf16<0, 4, 1><<<g600w, 256, 0, stream>>>(qbf, wqr_bf, bqr, nullptr, h1,
                                                  qb2, M6, 512, 256,
                                                  nullptr, nullptr);
  for (int l = 0; l < NL; ++l) {
    // fused ref-point + sampling -> flat
    k_sample<<<Mp, 256, 0, stream>>>(fcl, h1, w_r2, b_r2, boxes, flat);
    // Wp1: split-K x3 + reduce(relu+pmean) -> pvm
    k_wp1_split<<<gsk, 256, 0, stream>>>(flat, wp1_bf + (size_t)l * 256 * KP, part);
    k_wp1_reduce<<<600, 256, 0, stream>>>(part, bp1 + (size_t)l * DM, pvm);
    // kvb = bf16(pvm @ Wp2 + bp2)
    k_gemm_bf16<0, 6, 1><<<g600, 256, 0, stream>>>(pvm, wp2_bf + (size_t)l * DM * DM,
                                                   bp2 + (size_t)l * DM, nullptr, nullptr,
                                                   kvb, M6, DM, DM, nullptr, nullptr);
    k_attn<<<M6, 256, 0, stream>>>(qb2, kvb, ao);
    // queries += ao @ Wo + bo   (fp32 master + bf16 mirror)
    k_gemm_bf16<0, 2, 1><<<g600, 256, 0, stream>>>(ao, wo_bf + (size_t)l * DM * DM,
                                                   bo + (size_t)l * DM, queries, queries,
                                                   qbf, M6, DM, DM, nullptr, nullptr);
    // merged: hb = relu(q@w_b1+b_b1) | next-layer h1 (relu) | qb2 (bf16)
    int ln = (l + 1) % NL;
    k_gemm_bf16<0, 7, 1><<<g600m, 256, 0, stream>>>(qbf, wb1_bf, b_b1, (const float*)qb2,
                                                    hb, (ushort_t*)h1, M6, 768, 256,
                                                    wqr_bf + (size_t)ln * 512 * 256,
                                                    bqr + ln * 512);
    // box update (+ fused logits/boxes output on the last layer)
    k_boxf<<<M6, 256, 0, stream>>>(hb, w_b2, b_b2, boxes, (l == NL - 1) ? 1 : 0,
                                   queries, w_cls, b_cls, out);
  }
}

// Round 10
// 729.971 us; speedup vs baseline: 2.5901x; 1.0620x over previous
//
#include <hip/hip_runtime.h>
#include <hip/hip_bf16.h>
#include <math.h>

// Problem constants
#define BB 2
#define TT 4
#define CIN 128
#define DM 256
#define NQ 300
#define NP 8
#define PS 3
#define NL 6
#define HW 4096   // 64*64
#define KP 2304   // 3*3*256

typedef __attribute__((ext_vector_type(8))) short short8;
typedef __attribute__((ext_vector_type(4))) short short4_t;
typedef __attribute__((ext_vector_type(4))) float f32x4;
typedef unsigned short ushort_t;

static __device__ __forceinline__ ushort_t f2bf(float f) {
  __hip_bfloat16 h = __float2bfloat16(f);
  return *reinterpret_cast<ushort_t*>(&h);
}
static __device__ __forceinline__ float bf2f(ushort_t u) {
  return __uint_as_float(((unsigned)u) << 16);
}

// ---------------------------------------------------------------------------
// ONE mega prep kernel (block-range ladder):
//  [0,4064)       plain fp32->bf16 (w_in|w_lat|Wo|w_b1|w_r1|Wp1)
//  [4064,4320)    tct coeffs
//  [4320,6624)    wsm reorder
//  [6624,9696)    transposes: wp2t[l][d,o]=Wp2[l][o,d]; wqT[l][c,o]=Wq[l][o,c]
//  [9696,9708)    bqt[l][d]=bq.Wp2[:,d] ; bfuse[l][o2]=bp2.Wo[o2,:]+bo
//  [9708,10797)   zero x2p
//  [10797,10798)  bias_comb
//  [10798,11398)  queries/boxes init
__global__ void k_prep(const float* __restrict__ w_in, const float* __restrict__ w_lat,
                       const float* __restrict__ Wo, const float* __restrict__ w_b1,
                       const float* __restrict__ w_r1, const float* __restrict__ Wp1,
                       ushort_t* __restrict__ win_bf, ushort_t* __restrict__ wlat_bf,
                       ushort_t* __restrict__ wo_bf, ushort_t* __restrict__ wb1_bf,
                       ushort_t* __restrict__ wr1_bf, ushort_t* __restrict__ wp1_bf,
                       const float* __restrict__ w_tf, ushort_t* __restrict__ tct,
                       const float* __restrict__ w_sm, ushort_t* __restrict__ wsm_bf,
                       const float* __restrict__ Wp2, const float* __restrict__ Wq,
                       ushort_t* __restrict__ wp2t, ushort_t* __restrict__ wqT,
                       const float* __restrict__ bq, const float* __restrict__ bp2,
                       const float* __restrict__ bo,
                       float* __restrict__ bqt, float* __restrict__ bfuse,
                       uint4* __restrict__ x2p_zero,
                       const float* __restrict__ b_tf, const float* __restrict__ b_in,
                       float* __restrict__ bias_comb,
                       const float* __restrict__ qe, const float* __restrict__ qp,
                       const float* __restrict__ pb, float* __restrict__ queries,
                       ushort_t* __restrict__ qbf, float* __restrict__ boxes) {
  __shared__ float bt[128];
  int b = blockIdx.x, t = threadIdx.x;
  if (b < 4064) {
    int i = b * 256 + t;
    const float* s; ushort_t* d; int base;
    if (i < 8192)         { s = w_in;  d = win_bf;  base = 0; }
    else if (i < 24576)   { s = w_lat; d = wlat_bf; base = 8192; }
    else if (i < 122880)  { s = Wo;    d = wo_bf;   base = 24576; }
    else if (i < 139264)  { s = w_b1;  d = wb1_bf;  base = 122880; }
    else if (i < 155648)  { s = w_r1;  d = wr1_bf;  base = 139264; }
    else                  { s = Wp1;   d = wp1_bf;  base = 155648; }
    int j = i - base;
    float4 v = ((const float4*)s)[j];
    d[j * 4 + 0] = f2bf(v.x);
    d[j * 4 + 1] = f2bf(v.y);
    d[j * 4 + 2] = f2bf(v.z);
    d[j * 4 + 3] = f2bf(v.w);
  } else if (b < 4320) {
    int i = (b - 4064) * 256 + t;     // < 512*128
    int k = i >> 7, c = i & 127;
    int u = k >> 7, ci = k & 127;
    const float* wp = w_tf + ((size_t)(c * 128 + ci)) * 3;
    float w0 = wp[0], w1 = wp[1], w2 = wp[2];
    float coef = (u == 0) ? (w0 + w1) : (u == 3) ? (w1 + w2) : (w0 + w1 + w2);
    tct[(size_t)k * 128 + c] = f2bf(0.25f * coef);
  } else if (b < 6624) {
    int i = (b - 4320) * 256 + t;     // < 256*2304
    int n = i / KP;
    int r = i - n * KP;
    int tp = r >> 8, c = r & 255;
    wsm_bf[i] = f2bf(w_sm[((size_t)(n * 256 + c)) * 9 + tp]);
  } else if (b < 9696) {
    int i = (b - 6624) * 256 + t;     // < 786432
    if (i < 393216) {
      int l = i >> 16, r = i & 65535;
      int d = r >> 8, o = r & 255;
      wp2t[i] = f2bf(Wp2[((size_t)(l * 256 + o)) * 256 + d]);
    } else {
      int j = i - 393216;
      int l = j >> 16, r = j & 65535;
      int c = r >> 8, o = r & 255;
      wqT[j] = f2bf(Wq[((size_t)(l * 256 + o)) * 256 + c]);
    }
  } else if (b < 9708) {
    int i = (b - 9696) * 256 + t;     // < 3072
    if (i < 1536) {
      int l = i >> 8, d = i & 255;
      float a = 0.f;
      for (int o = 0; o < 256; ++o)
        a += bq[l * 256 + o] * Wp2[((size_t)(l * 256 + o)) * 256 + d];
      bqt[i] = a;
    } else {
      int j = i - 1536;
      int l = j >> 8, o2 = j & 255;
      float a = bo[l * 256 + o2];
      for (int o = 0; o < 256; ++o)
        a += bp2[l * 256 + o] * Wo[((size_t)(l * 256 + o2)) * 256 + o];
      bfuse[j] = a;
    }
  } else if (b < 10797) {
    int j = (b - 9708) * 256 + t;
    if (j < 278784) x2p_zero[j] = make_uint4(0u, 0u, 0u, 0u);
  } else if (b < 10798) {
    int d = t;
    if (d < 128) bt[d] = b_tf[d];
    __syncthreads();
    float a = b_in[d];
    for (int c = 0; c < 128; ++c) a += w_in[d * 128 + c] * bt[c];
    bias_comb[d] = a;
  } else {
    int i = (b - 10798) * 256 + t;
    if (i < BB * NQ * DM) {
      int rd = i % (NQ * DM);
      float v = qe[rd] + qp[rd];
      queries[i] = v;
      qbf[i] = f2bf(v);
    }
    if (i < BB * NQ * 4) boxes[i] = pb[i];
  }
}

// ---------------------------------------------------------------------------
// Batched weight-composition GEMM, grid (4,4,12):
//  z<6 : wqt[l]   = wp2t[l] x wqT[l]   (C[d,c] = sum_o Wp2[o,d] Wq[o,c])
//  z>=6: wfuse[l] = wo_bf[l] x wp2t[l] (C[o2,dd] = sum_o Wo[o2,o] Wp2[o,dd])
__global__ __launch_bounds__(256) void k_wcompose(const ushort_t* __restrict__ wp2t,
                                                  const ushort_t* __restrict__ wqT,
                                                  const ushort_t* __restrict__ wo_bf,
                                                  ushort_t* __restrict__ wqt,
                                                  ushort_t* __restrict__ wfuse) {
  __shared__ ushort_t As[64 * 36];
  __shared__ ushort_t Bs[64 * 36];
  int z = blockIdx.z, l = z % 6;
  const ushort_t* A;
  const ushort_t* W;
  ushort_t* C;
  if (z < 6) { A = wp2t + l * 65536; W = wqT + l * 65536; C = wqt + l * 65536; }
  else       { A = wo_bf + l * 65536; W = wp2t + l * 65536; C = wfuse + l * 65536; }
  int tid = threadIdx.x;
  int bm = blockIdx.x * 64, bn = blockIdx.y * 64;
  int w = tid >> 6, lane = tid & 63;
  int wm = (w & 1) * 32, wn = (w >> 1) * 32;
  int q = lane >> 4, ml = lane & 15;
  f32x4 acc[2][2] = {};
  int srow = tid >> 2, scol = (tid & 3) * 8;
  const ushort_t* Ag = A + (size_t)(bm + srow) * 256 + scol;
  const ushort_t* Wg = W + (size_t)(bn + srow) * 256 + scol;
  for (int k0 = 0; k0 < 256; k0 += 32) {
    short8 av = *(const short8*)(Ag + k0);
    short8 wv = *(const short8*)(Wg + k0);
    *(short8*)(As + srow * 36 + scol) = av;
    *(short8*)(Bs + srow * 36 + scol) = wv;
    __syncthreads();
    short8 a0 = *(const short8*)(As + (wm + ml) * 36 + q * 8);
    short8 a1 = *(const short8*)(As + (wm + 16 + ml) * 36 + q * 8);
    short8 b0 = *(const short8*)(Bs + (wn + ml) * 36 + q * 8);
    short8 b1 = *(const short8*)(Bs + (wn + 16 + ml) * 36 + q * 8);
    acc[0][0] = __builtin_amdgcn_mfma_f32_16x16x32_bf16(a0, b0, acc[0][0], 0, 0, 0);
    acc[0][1] = __builtin_amdgcn_mfma_f32_16x16x32_bf16(a0, b1, acc[0][1], 0, 0, 0);
    acc[1][0] = __builtin_amdgcn_mfma_f32_16x16x32_bf16(a1, b0, acc[1][0], 0, 0, 0);
    acc[1][1] = __builtin_amdgcn_mfma_f32_16x16x32_bf16(a1, b1, acc[1][1], 0, 0, 0);
    __syncthreads();
  }
#pragma unroll
  for (int i = 0; i < 2; ++i)
#pragma unroll
    for (int j = 0; j < 2; ++j) {
      int cn = bn + wn + j * 16 + ml;
#pragma unroll
      for (int r = 0; r < 4; ++r) {
        int rm = bm + wm + i * 16 + q * 4 + r;
        C[(size_t)rm * 256 + cn] = f2bf(acc[i][j][r]);
      }
    }
}

// ---------------------------------------------------------------------------
// Transpose+convert: feat (b,u,ci,s) fp32 -> featT (b*HW+s, u*128+ci) bf16.
__global__ __launch_bounds__(256) void k_tr(const float* __restrict__ feat,
                                            ushort_t* __restrict__ featT) {
  __shared__ float ldsF[64][65];
  int tid = threadIdx.x;
  int gs = blockIdx.x;
  int b = gs >> 6;
  int s0 = (gs & 63) * 64;
  int k0 = blockIdx.y * 64;
  int kk = tid >> 2, sc0 = (tid & 3) * 16;
  {
    int k = k0 + kk;
    int u = k >> 7, ci = k & 127;
    const float* src = feat + (((size_t)(b * 4 + u) * 128 + ci) << 12) + s0 + sc0;
#pragma unroll
    for (int j = 0; j < 4; ++j) {
      float4 v = *(const float4*)(src + j * 4);
      ldsF[kk][sc0 + j * 4 + 0] = v.x;
      ldsF[kk][sc0 + j * 4 + 1] = v.y;
      ldsF[kk][sc0 + j * 4 + 2] = v.z;
      ldsF[kk][sc0 + j * 4 + 3] = v.w;
    }
  }
  __syncthreads();
#pragma unroll
  for (int p = 0; p < 2; ++p) {
    int idx = p * 256 + tid;
    int s_l = idx >> 3, kc = (idx & 7) * 8;
    short8 v;
#pragma unroll
    for (int j = 0; j < 8; ++j) v[j] = (short)f2bf(ldsF[kc + j][s_l]);
    *(short8*)(featT + (size_t)(b * 4096 + s0 + s_l) * 512 + k0 + kc) = v;
  }
}

// ---------------------------------------------------------------------------
// Backbone GEMM: xcl = bf16(featT . Wcomb^T + biasc + pos). BM=32, BN=64.
__global__ __launch_bounds__(256) void k_feat2(const ushort_t* __restrict__ featT,
                                               const ushort_t* __restrict__ wcomb,
                                               const float* __restrict__ biasc,
                                               ushort_t* __restrict__ xcl) {
  __shared__ ushort_t As[32 * 36];
  __shared__ ushort_t Bs[64 * 36];
  __shared__ float dimt_s[256];
  int tid = threadIdx.x;
  {
    int dd = tid & 127;
    int ii = dd >> 1;
    dimt_s[tid] = powf(10000.0f, (2.0f * (float)(ii >> 1)) / 64.0f);
  }
  int bm = blockIdx.x * 32, bn = blockIdx.y * 64;
  int w = tid >> 6, lane = tid & 63;
  int wm = (w & 1) * 16, wn = (w >> 1) * 32;
  int q = lane >> 4, ml = lane & 15;
  int sra = tid >> 3, sca = (tid & 7) * 4;
  int srb = tid >> 2, scb = (tid & 3) * 8;
  const ushort_t* Ag = featT + (size_t)(bm + sra) * 512 + sca;
  const ushort_t* Wg = wcomb + (size_t)(bn + srb) * 512 + scb;
  f32x4 acc[2] = {};
  short4_t av = *(const short4_t*)Ag;
  short8 wv = *(const short8*)Wg;
  for (int k0 = 0; k0 < 512; k0 += 32) {
    *(short4_t*)(As + sra * 36 + sca) = av;
    *(short8*)(Bs + srb * 36 + scb) = wv;
    __syncthreads();
    if (k0 + 32 < 512) {
      av = *(const short4_t*)(Ag + k0 + 32);
      wv = *(const short8*)(Wg + k0 + 32);
    }
    short8 a = *(const short8*)(As + (wm + ml) * 36 + q * 8);
    short8 b0 = *(const short8*)(Bs + (wn + ml) * 36 + q * 8);
    short8 b1 = *(const short8*)(Bs + (wn + 16 + ml) * 36 + q * 8);
    acc[0] = __builtin_amdgcn_mfma_f32_16x16x32_bf16(a, b0, acc[0], 0, 0, 0);
    acc[1] = __builtin_amdgcn_mfma_f32_16x16x32_bf16(a, b1, acc[1], 0, 0, 0);
    __syncthreads();
  }
  const float FKT = 6.28318530717958647692f / 64.000001f;
#pragma unroll
  for (int j = 0; j < 2; ++j) {
    int cn = bn + wn + j * 16 + ml;
    float dimt = dimt_s[cn];
    float bC = biasc[cn];
    bool isx = cn >= 128;
    bool isc = cn & 1;
#pragma unroll
    for (int r = 0; r < 4; ++r) {
      int rm = bm + wm + q * 4 + r;
      int s = rm & 4095;
      int y = s >> 6, x = s & 63;
      float ang = (float)((isx ? x : y) + 1) * FKT / dimt;
      float pos = isc ? cosf(ang) : sinf(ang);
      xcl[(size_t)rm * 256 + cn] = f2bf(acc[j][r] + bC + pos);
    }
  }
}

// ---------------------------------------------------------------------------
// bf16 MFMA GEMM, BM=BN=64, BK=32.
// OUTMODE: 0 fp32 C (bias+ACT); 1 bf16 padded (B,66,66,256);
//          2 fp32 C + bf16 mirror + residual;
//          4 N=512, weights W|W2 per 256-seg: n<256 relu->Cf, else bf16->Cb;
//          6 plain bf16 out;
//          7 N=768, weights W|W2|W3 per 256-seg: n<256 relu->Cf(hb),
//            256..511 relu->(float*)Cb (h1), 512..767 bf16->(ushort*)res (qt).
template <int ACT, int OUTMODE, int MG>
__global__ __launch_bounds__(256) void k_gemm_bf16(const ushort_t* __restrict__ A,
                                                   const ushort_t* __restrict__ W,
                                                   const float* __restrict__ bias,
                                                   const float* __restrict__ res,
                                                   float* __restrict__ Cf,
                                                   ushort_t* __restrict__ Cb,
                                                   int M, int N, int K,
                                                   const ushort_t* __restrict__ W2,
                                                   const float* __restrict__ bias2,
                                                   const ushort_t* __restrict__ W3,
                                                   const float* __restrict__ bias3) {
  __shared__ ushort_t As[64 * 36];
  __shared__ ushort_t Bs[64 * 36];
  int tid = threadIdx.x;
  int bm = blockIdx.x * 64, bn = blockIdx.y * 64;
  int w = tid >> 6, lane = tid & 63;
  int wm = (w & 1) * 32, wn = (w >> 1) * 32;
  int q = lane >> 4, ml = lane & 15;
  f32x4 acc[2][2] = {};
  int srow = tid >> 2, scol = (tid & 3) * 8;
  int ga = bm + srow;
  if (MG) ga = min(ga, M - 1);
  const ushort_t* Ag = A + (size_t)ga * K + scol;
  const ushort_t* Wg;
  if (OUTMODE == 7) {
    int seg = bn >> 8;
    const ushort_t* Wb = (seg == 0) ? W : ((seg == 1) ? W2 : W3);
    Wg = Wb + (size_t)((bn & 255) + srow) * K + scol;
  } else if (OUTMODE == 4) {
    const ushort_t* Wb = (bn < 256) ? W : W2;
    Wg = Wb + (size_t)((bn & 255) + srow) * K + scol;
  } else {
    Wg = W + (size_t)(bn + srow) * K + scol;
  }
  for (int k0 = 0; k0 < K; k0 += 32) {
    short8 av = *(const short8*)(Ag + k0);
    short8 wv = *(const short8*)(Wg + k0);
    *(short8*)(As + srow * 36 + scol) = av;
    *(short8*)(Bs + srow * 36 + scol) = wv;
    __syncthreads();
    short8 a0 = *(const short8*)(As + (wm + ml) * 36 + q * 8);
    short8 a1 = *(const short8*)(As + (wm + 16 + ml) * 36 + q * 8);
    short8 b0 = *(const short8*)(Bs + (wn + ml) * 36 + q * 8);
    short8 b1 = *(const short8*)(Bs + (wn + 16 + ml) * 36 + q * 8);
    acc[0][0] = __builtin_amdgcn_mfma_f32_16x16x32_bf16(a0, b0, acc[0][0], 0, 0, 0);
    acc[0][1] = __builtin_amdgcn_mfma_f32_16x16x32_bf16(a0, b1, acc[0][1], 0, 0, 0);
    acc[1][0] = __builtin_amdgcn_mfma_f32_16x16x32_bf16(a1, b0, acc[1][0], 0, 0, 0);
    acc[1][1] = __builtin_amdgcn_mfma_f32_16x16x32_bf16(a1, b1, acc[1][1], 0, 0, 0);
    __syncthreads();
  }
#pragma unroll
  for (int i = 0; i < 2; ++i) {
#pragma unroll
    for (int j = 0; j < 2; ++j) {
      int cn = bn + wn + j * 16 + ml;
      float bsv;
      if (OUTMODE == 7) {
        int seg = cn >> 8;
        bsv = ((seg == 0) ? bias : ((seg == 1) ? bias2 : bias3))[cn & 255];
      } else if (OUTMODE == 4) {
        bsv = ((cn < 256) ? bias : bias2)[cn & 255];
      } else {
        bsv = bias ? bias[cn] : 0.f;
      }
#pragma unroll
      for (int r = 0; r < 4; ++r) {
        int rm = bm + wm + i * 16 + q * 4 + r;
        if (MG && rm >= M) continue;
        float v = acc[i][j][r] + bsv;
        if (OUTMODE == 0) {
          if (ACT == 1) v = fmaxf(v, 0.f);
          Cf[(size_t)rm * N + cn] = v;
        } else if (OUTMODE == 1) {
          int b = rm >> 12, rem = rm & 4095;
          int y = rem >> 6, xx = rem & 63;
          Cb[(((size_t)(b * 66 + y + 1)) * 66 + xx + 1) * 256 + cn] = f2bf(v);
        } else if (OUTMODE == 2) {
          v += res[(size_t)rm * N + cn];
          Cf[(size_t)rm * N + cn] = v;
          Cb[(size_t)rm * N + cn] = f2bf(v);
        } else if (OUTMODE == 4) {
          if (cn < 256) Cf[(size_t)rm * 256 + cn] = fmaxf(v, 0.f);
          else Cb[(size_t)rm * 256 + (cn & 255)] = f2bf(v);
        } else if (OUTMODE == 6) {
          Cb[(size_t)rm * N + cn] = f2bf(v);
        } else if (OUTMODE == 7) {
          if (cn < 256) Cf[(size_t)rm * 256 + cn] = fmaxf(v, 0.f);
          else if (cn < 512) ((float*)Cb)[(size_t)rm * 256 + (cn & 255)] = fmaxf(v, 0.f);
          else ((ushort_t*)res)[(size_t)rm * 256 + (cn & 255)] = f2bf(v);
        }
      }
    }
  }
}

// ---------------------------------------------------------------------------
// Wp1 split-K phase 1: grid (75,4,3), 64x64 tile, prefetched; bf16 partials.
__global__ __launch_bounds__(256) void k_wp1_split(const ushort_t* __restrict__ A,
                                                   const ushort_t* __restrict__ W,
                                                   ushort_t* __restrict__ part) {
  __shared__ ushort_t As[64 * 36];
  __shared__ ushort_t Bs[64 * 36];
  int tid = threadIdx.x;
  int bm = blockIdx.x * 64, bn = blockIdx.y * 64;
  int kz = blockIdx.z * 768;
  int w = tid >> 6, lane = tid & 63;
  int wm = (w & 1) * 32, wn = (w >> 1) * 32;
  int q = lane >> 4, ml = lane & 15;
  int srow = tid >> 2, scol = (tid & 3) * 8;
  const ushort_t* Ag = A + (size_t)(bm + srow) * KP + kz + scol;
  const ushort_t* Wg = W + (size_t)(bn + srow) * KP + kz + scol;
  f32x4 acc[2][2] = {};
  short8 av = *(const short8*)(Ag);
  short8 wv = *(const short8*)(Wg);
  for (int k0 = 0; k0 < 768; k0 += 32) {
    *(short8*)(As + srow * 36 + scol) = av;
    *(short8*)(Bs + srow * 36 + scol) = wv;
    __syncthreads();
    if (k0 + 32 < 768) {
      av = *(const short8*)(Ag + k0 + 32);
      wv = *(const short8*)(Wg + k0 + 32);
    }
    short8 a0 = *(const short8*)(As + (wm + ml) * 36 + q * 8);
    short8 a1 = *(const short8*)(As + (wm + 16 + ml) * 36 + q * 8);
    short8 b0 = *(const short8*)(Bs + (wn + ml) * 36 + q * 8);
    short8 b1 = *(const short8*)(Bs + (wn + 16 + ml) * 36 + q * 8);
    acc[0][0] = __builtin_amdgcn_mfma_f32_16x16x32_bf16(a0, b0, acc[0][0], 0, 0, 0);
    acc[0][1] = __builtin_amdgcn_mfma_f32_16x16x32_bf16(a0, b1, acc[0][1], 0, 0, 0);
    acc[1][0] = __builtin_amdgcn_mfma_f32_16x16x32_bf16(a1, b0, acc[1][0], 0, 0, 0);
    acc[1][1] = __builtin_amdgcn_mfma_f32_16x16x32_bf16(a1, b1, acc[1][1], 0, 0, 0);
    __syncthreads();
  }
  ushort_t* pz = part + (size_t)blockIdx.z * 4800 * 256;
#pragma unroll
  for (int i = 0; i < 2; ++i)
#pragma unroll
    for (int j = 0; j < 2; ++j) {
      int cn = bn + wn + j * 16 + ml;
#pragma unroll
      for (int r = 0; r < 4; ++r) {
        int rm = bm + wm + i * 16 + q * 4 + r;
        pz[(size_t)rm * 256 + cn] = f2bf(acc[i][j][r]);
      }
    }
}

// Wp1 split-K phase 2: pvm = bf16( mean_p relu( sum_z part + bias ) )
__global__ __launch_bounds__(256) void k_wp1_reduce(const ushort_t* __restrict__ part,
                                                    const float* __restrict__ bias,
                                                    ushort_t* __restrict__ pvm) {
  int row = blockIdx.x;   // 600
  int d = threadIdx.x;
  float b = bias[d];
  float s = 0.f;
#pragma unroll
  for (int p = 0; p < 8; ++p) {
    size_t idx = (size_t)(row * 8 + p) * 256 + d;
    float v = bf2f(part[idx]) + bf2f(part[idx + (size_t)4800 * 256]) +
              bf2f(part[idx + (size_t)2 * 4800 * 256]) + b;
    s += fmaxf(v, 0.f);
  }
  pvm[(size_t)row * 256 + d] = f2bf(s * 0.125f);
}

// ---------------------------------------------------------------------------
// 3x3 conv as GEMM, BM=32, BN=64, grid (256,4)=1024 blocks, prefetched.
__global__ __launch_bounds__(256) void k_conv3(const ushort_t* __restrict__ x2p,
                                               const ushort_t* __restrict__ wsm,
                                               const float* __restrict__ bsm,
                                               ushort_t* __restrict__ fcl) {
  __shared__ ushort_t As[32 * 36];
  __shared__ ushort_t Bs[64 * 36];
  int tid = threadIdx.x;
  int bm = blockIdx.x * 32, bn = blockIdx.y * 64;
  int w = tid >> 6, lane = tid & 63;
  int wm = (w & 1) * 16, wn = (w >> 1) * 32;
  int q = lane >> 4, ml = lane & 15;
  int sra = tid >> 3, sca = (tid & 7) * 4;
  int srb = tid >> 2, scb = (tid & 3) * 8;
  int sA = bm + sra;
  int b = sA >> 12, rem = sA & 4095;
  size_t pbase = ((size_t)(b * 66 + (rem >> 6)) * 66 + (rem & 63)) * 256;
  const ushort_t* Wg = wsm + (size_t)(bn + srb) * KP + scb;
  auto loadA = [&](int k0) {
    int ka = k0 + sca;
    int t9 = ka >> 8;
    int ky = t9 / 3, kx = t9 - ky * 3;
    return *(const short4_t*)(x2p + pbase + (size_t)(ky * 66 + kx) * 256 + (ka & 255));
  };
  f32x4 acc[2] = {};
  short4_t av = loadA(0);
  short8 wv = *(const short8*)(Wg);
  for (int k0 = 0; k0 < KP; k0 += 32) {
    *(short4_t*)(As + sra * 36 + sca) = av;
    *(short8*)(Bs + srb * 36 + scb) = wv;
    __syncthreads();
    if (k0 + 32 < KP) {
      av = loadA(k0 + 32);
      wv = *(const short8*)(Wg + k0 + 32);
    }
    short8 a = *(const short8*)(As + (wm + ml) * 36 + q * 8);
    short8 b0 = *(const short8*)(Bs + (wn + ml) * 36 + q * 8);
    short8 b1 = *(const short8*)(Bs + (wn + 16 + ml) * 36 + q * 8);
    acc[0] = __builtin_amdgcn_mfma_f32_16x16x32_bf16(a, b0, acc[0], 0, 0, 0);
    acc[1] = __builtin_amdgcn_mfma_f32_16x16x32_bf16(a, b1, acc[1], 0, 0, 0);
    __syncthreads();
  }
#pragma unroll
  for (int j = 0; j < 2; ++j) {
    int cn = bn + wn + j * 16 + ml;
    float bsv = bsm[cn];
#pragma unroll
    for (int r = 0; r < 4; ++r) {
      int rm = bm + wm + q * 4 + r;
      fcl[(size_t)rm * 256 + cn] = f2bf(acc[j][r] + bsv);
    }
  }
}

// ---------------------------------------------------------------------------
// Fused r2ref + bilinear patch sampling. Block per (b,q,p); thread = channel.
__global__ __launch_bounds__(256) void k_sample(const ushort_t* __restrict__ fcl,
                                                const float* __restrict__ h1,
                                                const float* __restrict__ w_r2,
                                                const float* __restrict__ b_r2,
                                                const float* __restrict__ boxes,
                                                ushort_t* __restrict__ flat) {
  __shared__ float pr[8];
  __shared__ float bc2[2];
  int blk = blockIdx.x;
  int row = blk >> 3, p = blk & 7;
  int b = row / NQ;
  int tid = threadIdx.x;
  float h = h1[(size_t)row * 256 + tid];
  float px = h * w_r2[(size_t)(2 * p) * 256 + tid];
  float py = h * w_r2[(size_t)(2 * p + 1) * 256 + tid];
#pragma unroll
  for (int s = 32; s > 0; s >>= 1) {
    px += __shfl_down(px, s, 64);
    py += __shfl_down(py, s, 64);
  }
  int w = tid >> 6, lane = tid & 63;
  if (lane == 0) { pr[w * 2] = px; pr[w * 2 + 1] = py; }
  __syncthreads();
  if (tid == 0) {
    float sx = pr[0] + pr[2] + pr[4] + pr[6] + b_r2[2 * p];
    float sy = pr[1] + pr[3] + pr[5] + pr[7] + b_r2[2 * p + 1];
    float rx = boxes[row * 4 + 0] + 0.5f * tanhf(sx);
    float ry = boxes[row * 4 + 1] + 0.5f * tanhf(sy);
    bc2[0] = fminf(fmaxf(rx, 0.f), 1.f);
    bc2[1] = fminf(fmaxf(ry, 0.f), 1.f);
  }
  __syncthreads();
  float rx = bc2[0], ry = bc2[1];
  int c = tid;
  const ushort_t* fb = fcl + (size_t)b * HW * DM;
  ushort_t* op = flat + (size_t)blk * KP;
#pragma unroll
  for (int jy = 0; jy < 3; ++jy) {
    float yy = (ry + (float)(jy - 1) * (1.0f / 64.0f)) * 63.0f;
    yy = fminf(fmaxf(yy, 0.f), 63.0f);
    float y0f = floorf(yy);
    float wy = yy - y0f;
    int y0 = (int)y0f;
    int y1 = min(y0 + 1, 63);
#pragma unroll
    for (int jx = 0; jx < 3; ++jx) {
      float xx = (rx + (float)(jx - 1) * (1.0f / 64.0f)) * 63.0f;
      xx = fminf(fmaxf(xx, 0.f), 63.0f);
      float x0f = floorf(xx);
      float wx = xx - x0f;
      int x0 = (int)x0f;
      int x1 = min(x0 + 1, 63);
      float v00 = bf2f(fb[(y0 * 64 + x0) * DM + c]);
      float v01 = bf2f(fb[(y0 * 64 + x1) * DM + c]);
      float v10 = bf2f(fb[(y1 * 64 + x0) * DM + c]);
      float v11 = bf2f(fb[(y1 * 64 + x1) * DM + c]);
      float v = v00 * (1.f - wx) * (1.f - wy) + v01 * wx * (1.f - wy) +
                v10 * (1.f - wx) * wy + v11 * wx * wy;
      op[(jy * 3 + jx) * DM + c] = f2bf(v);
    }
  }
}

// ---------------------------------------------------------------------------
// Attention in the Wp2-commuted basis: scores = qt . pvm_k / 16 (row-const
// from bp2 drops out of softmax); ctx = P @ pvm (bf16 out).
__global__ __launch_bounds__(256) void k_attn(const ushort_t* __restrict__ qt,
                                              const ushort_t* __restrict__ pvm,
                                              ushort_t* __restrict__ ctx) {
  __shared__ float qs[256];
  __shared__ float sc[512];
  __shared__ float red[256];
  int row = blockIdx.x;
  int b = row / NQ;
  int tid = threadIdx.x;
  qs[tid] = bf2f(qt[(size_t)row * DM + tid]);
  __syncthreads();
  const ushort_t* kvB = pvm + (size_t)b * NQ * DM;
#pragma unroll
  for (int s2 = 0; s2 < 2; ++s2) {
    int k = tid + s2 * 256;
    float v = -1e30f;
    if (k < NQ) {
      const ushort_t* kp = kvB + (size_t)k * DM;
      float a = 0.f;
#pragma unroll
      for (int d = 0; d < 256; d += 8) {
        short8 k8 = *(const short8*)(kp + d);
        const float* qd = qs + d;
        a += bf2f((ushort_t)k8[0]) * qd[0];
        a += bf2f((ushort_t)k8[1]) * qd[1];
        a += bf2f((ushort_t)k8[2]) * qd[2];
        a += bf2f((ushort_t)k8[3]) * qd[3];
        a += bf2f((ushort_t)k8[4]) * qd[4];
        a += bf2f((ushort_t)k8[5]) * qd[5];
        a += bf2f((ushort_t)k8[6]) * qd[6];
        a += bf2f((ushort_t)k8[7]) * qd[7];
      }
      v = a * (1.0f / 16.0f);
    }
    sc[k] = v;
  }
  __syncthreads();
  red[tid] = fmaxf(sc[tid], sc[tid + 256]);
  __syncthreads();
  for (int st = 128; st > 0; st >>= 1) {
    if (tid < st) red[tid] = fmaxf(red[tid], red[tid + st]);
    __syncthreads();
  }
  float mx = red[0];
  __syncthreads();
  float e0 = (tid < NQ) ? expf(sc[tid] - mx) : 0.f;
  float e1 = (tid + 256 < NQ) ? expf(sc[tid + 256] - mx) : 0.f;
  sc[tid] = e0;
  sc[tid + 256] = e1;
  red[tid] = e0 + e1;
  __syncthreads();
  for (int st = 128; st > 0; st >>= 1) {
    if (tid < st) red[tid] += red[tid + st];
    __syncthreads();
  }
  float inv = 1.0f / red[0];
  __syncthreads();
  float acc = 0.f;
#pragma unroll 4
  for (int k = 0; k < NQ; ++k)
    acc += sc[k] * bf2f(kvB[(size_t)k * DM + tid]);
  ctx[(size_t)row * DM + tid] = f2bf(acc * inv);
}

// ---------------------------------------------------------------------------
// box update (+ fused final-output when last != 0).
__global__ __launch_bounds__(256) void k_boxf(const float* __restrict__ hb,
                                              const float* __restrict__ w_b2,
                                              const float* __restrict__ b_b2,
                                              float* __restrict__ boxes,
                                              int last,
                                              const float* __restrict__ queries,
                                              const float* __restrict__ w_cls,
                                              const float* __restrict__ b_cls,
                                              float* __restrict__ out) {
  __shared__ float nb[4];
  int row = blockIdx.x;
  int tid = threadIdx.x;
  int j = tid >> 6, lane = tid & 63;
  float4 hv = *(const float4*)(hb + (size_t)row * 256 + lane * 4);
  float4 wv = *(const float4*)(w_b2 + (size_t)j * 256 + lane * 4);
  float aa = hv.x * wv.x + hv.y * wv.y + hv.z * wv.z + hv.w * wv.w;
#pragma unroll
  for (int s = 32; s > 0; s >>= 1) aa += __shfl_down(aa, s, 64);
  if (lane == 0) {
    aa += b_b2[j];
    float delta = 1.0f / (1.0f + expf(-aa));
    float v = boxes[row * 4 + j] + 0.1f * tanhf(delta - 0.5f);
    v = fminf(fmaxf(v, 0.f), 1.f);
    boxes[row * 4 + j] = v;
    nb[j] = v;
  }
  if (last) {
    __syncthreads();
    if (j == 0) {
      float4 qv = *(const float4*)(queries + (size_t)row * 256 + lane * 4);
      float4 cv = *(const float4*)(w_cls + lane * 4);
      float a2 = qv.x * cv.x + qv.y * cv.y + qv.z * cv.z + qv.w * cv.w;
#pragma unroll
      for (int s = 32; s > 0; s >>= 1) a2 += __shfl_down(a2, s, 64);
      if (lane == 0) out[row] = a2 + b_cls[0];
    } else if (j == 1 && lane < 4) {
      out[600 + row * 4 + lane] = nb[lane];
    }
  }
}

// ---------------------------------------------------------------------------
extern "C" void kernel_launch(void* const* d_in, const int* in_sizes, int n_in,
                              void* d_out, int out_size, void* d_ws, size_t ws_size,
                              hipStream_t stream) {
  const float* feat   = (const float*)d_in[0];
  const float* pb     = (const float*)d_in[1];
  const float* w_tf   = (const float*)d_in[2];
  const float* b_tf   = (const float*)d_in[3];
  const float* w_in   = (const float*)d_in[4];
  const float* b_in   = (const float*)d_in[5];
  const float* w_lat  = (const float*)d_in[6];
  const float* b_lat  = (const float*)d_in[7];
  const float* w_sm   = (const float*)d_in[8];
  const float* b_sm   = (const float*)d_in[9];
  const float* q_embed= (const float*)d_in[10];
  const float* q_pos  = (const float*)d_in[11];
  const float* Wq     = (const float*)d_in[12];
  const float* bq     = (const float*)d_in[13];
  const float* Wo     = (const float*)d_in[14];
  const float* bo     = (const float*)d_in[15];
  const float* Wp1    = (const float*)d_in[16];
  const float* bp1    = (const float*)d_in[17];
  const float* Wp2    = (const float*)d_in[18];
  const float* bp2    = (const float*)d_in[19];
  const float* w_r1   = (const float*)d_in[20];
  const float* b_r1   = (const float*)d_in[21];
  const float* w_r2   = (const float*)d_in[22];
  const float* b_r2   = (const float*)d_in[23];
  const float* w_b1   = (const float*)d_in[24];
  const float* b_b1   = (const float*)d_in[25];
  const float* w_b2   = (const float*)d_in[26];
  const float* b_b2   = (const float*)d_in[27];
  const float* w_cls  = (const float*)d_in[28];
  const float* b_cls  = (const float*)d_in[29];
  float* out = (float*)d_out;

  float* ws = (float*)d_ws;
  size_t off = 0;
  auto alloc = [&](size_t n) { float* p = ws + off; off += n; return p; };
  ushort_t* flat    = (ushort_t*)alloc(5529600);   // 4800 x 2304 bf16
  ushort_t* part    = (ushort_t*)alloc(1843200);   // 3 x 4800 x 256 bf16
  ushort_t* featT   = (ushort_t*)alloc(2097152);   // 8192 x 512 bf16
  ushort_t* xcl     = (ushort_t*)alloc(1048576);   // 8192 x 256 bf16
  ushort_t* x2p     = (ushort_t*)alloc(1115136);   // 2 x 66 x 66 x 256 bf16
  ushort_t* fcl     = (ushort_t*)alloc(1048576);   // 8192 x 256 bf16
  ushort_t* wcomb   = (ushort_t*)alloc(65536);     // 256 x 512 bf16
  ushort_t* tct     = (ushort_t*)alloc(32768);     // 512 x 128 bf16
  ushort_t* win_bf  = (ushort_t*)alloc(16384);     // 256 x 128 bf16
  float*    biasc   = alloc(256);
  ushort_t* wlat_bf = (ushort_t*)alloc(32768);
  ushort_t* wsm_bf  = (ushort_t*)alloc(294912);
  ushort_t* wp1_bf  = (ushort_t*)alloc(1769472);   // 6 x 256 x 2304
  ushort_t* wo_bf   = (ushort_t*)alloc(196608);    // 6 x 256 x 256
  ushort_t* wb1_bf  = (ushort_t*)alloc(32768);
  ushort_t* wr1_bf  = (ushort_t*)alloc(32768);
  ushort_t* wp2t    = (ushort_t*)alloc(196608);    // Wp2^T per layer
  ushort_t* wqT     = (ushort_t*)alloc(196608);    // Wq^T per layer
  ushort_t* wqt_bf  = (ushort_t*)alloc(196608);    // composed Wqt
  ushort_t* wfuse_bf= (ushort_t*)alloc(196608);    // composed Wo@Wp2
  float*    bqt     = alloc(1536);                 // 6 x 256
  float*    bfuse   = alloc(1536);                 // 6 x 256
  float* queries = alloc(153600);
  ushort_t* qbf  = (ushort_t*)alloc(76800);
  float* h1      = alloc(153600);
  ushort_t* qt   = (ushort_t*)alloc(76800);        // bf16 qt for attention
  ushort_t* ctx  = (ushort_t*)alloc(76800);
  float* hb      = alloc(153600);
  ushort_t* pvm  = (ushort_t*)alloc(76800);
  float* boxes   = alloc(2400);
  (void)ws_size; (void)in_sizes; (void)n_in; (void)out_size;

  // --- prep ---
  k_prep<<<11398, 256, 0, stream>>>(w_in, w_lat, Wo, w_b1, w_r1, Wp1,
                                    win_bf, wlat_bf, wo_bf, wb1_bf, wr1_bf, wp1_bf,
                                    w_tf, tct, w_sm, wsm_bf,
                                    Wp2, Wq, wp2t, wqT,
                                    bq, bp2, bo, bqt, bfuse,
                                    (uint4*)x2p, b_tf, b_in, biasc,
                                    q_embed, q_pos, pb, queries, qbf, boxes);
  k_gemm_bf16<0, 6, 0><<<dim3(4, 8), 256, 0, stream>>>(win_bf, tct, nullptr, nullptr,
                                                       nullptr, wcomb, 256, 512, 128,
                                                       nullptr, nullptr, nullptr, nullptr);
  k_wcompose<<<dim3(4, 4, 12), 256, 0, stream>>>(wp2t, wqT, wo_bf, wqt_bf, wfuse_bf);

  // --- backbone ---
  k_tr<<<dim3(128, 8), 256, 0, stream>>>(feat, featT);
  k_feat2<<<dim3(256, 4), 256, 0, stream>>>(featT, wcomb, biasc, xcl);
  k_gemm_bf16<0, 1, 0><<<dim3(128, 4), 256, 0, stream>>>(xcl, wlat_bf, b_lat, nullptr,
                                                         nullptr, x2p, BB * HW, 256, 256,
                                                         nullptr, nullptr, nullptr, nullptr);
  k_conv3<<<dim3(256, 4), 256, 0, stream>>>(x2p, wsm_bf, b_sm, fcl);

  const int M6 = BB * NQ;                 // 600
  const int Mp = BB * NQ * NP;            // 4800
  dim3 g600((M6 + 63) / 64, 4);           // (10,4)
  dim3 g600w((M6 + 63) / 64, 8);          // (10,8)
  dim3 g600m((M6 + 63) / 64, 12);         // (10,12) merged N=768
  dim3 gsk(Mp / 64, 4, 3);                // (75,4,3) split-K

  // layer-0: h1 = relu(q@w_r1+b_r1) | qt = bf16(q@Wqt[0]+bqt[0])
  k_gemm_bf16<0, 4, 1><<<g600w, 256, 0, stream>>>(qbf, wr1_bf, b_r1, nullptr, h1,
                                                  qt, M6, 512, 256,
                                                  wqt_bf, bqt, nullptr, nullptr);
  for (int l = 0; l < NL; ++l) {
    // fused ref-point + sampling -> flat
    k_sample<<<Mp, 256, 0, stream>>>(fcl, h1, w_r2, b_r2, boxes, flat);
    // Wp1: split-K x3 (bf16 partials) + reduce(relu+pmean) -> pvm
    k_wp1_split<<<gsk, 256, 0, stream>>>(flat, wp1_bf + (size_t)l * 256 * KP, part);
    k_wp1_reduce<<<600, 256, 0, stream>>>(part, bp1 + (size_t)l * DM, pvm);
    // attention in commuted basis: ctx = softmax(qt.pvm^T/16) @ pvm
    k_attn<<<M6, 256, 0, stream>>>(qt, pvm, ctx);
    // queries += ctx @ Wfuse[l]^T + bfuse[l]   (fp32 master + bf16 mirror)
    k_gemm_bf16<0, 2, 1><<<g600, 256, 0, stream>>>(ctx, wfuse_bf + (size_t)l * 65536,
                                                   bfuse + l * 256, queries, queries,
                                                   qbf, M6, DM, DM,
                                                   nullptr, nullptr, nullptr, nullptr);
    // merged: hb=relu(q@w_b1) | h1=relu(q@w_r1) | qt=bf16(q@Wqt[l+1])
    int ln = (l + 1) % NL;
    k_gemm_bf16<0, 7, 1><<<g600m, 256, 0, stream>>>(qbf, wb1_bf, b_b1, (const float*)qt,
                                                    hb, (ushort_t*)h1, M6, 768, 256,
                                                    wr1_bf, b_r1,
                                                    wqt_bf + (size_t)ln * 65536,
                                                    bqt + ln * 256);
    // box update (+ fused logits/boxes output on the last layer)
    k_boxf<<<M6, 256, 0, stream>>>(hb, w_b2, b_b2, boxes, (l == NL - 1) ? 1 : 0,
                                   queries, w_cls, b_cls, out);
  }
}